// Round 7
// baseline (530.698 us; speedup 1.0000x reference)
//
#include <hip/hip_runtime.h>
#include <hip/hip_bf16.h>
#include <math.h>

#define N_NODES 50000
#define F_IN 256
#define H1 128
#define C_OUT 40
#define L1W 384   // 3*H1
#define L2W 120   // 3*C_OUT
#define L2WP 128  // padded

typedef __attribute__((ext_vector_type(8))) short short8;
typedef __attribute__((ext_vector_type(4))) float f32x4;
typedef __attribute__((ext_vector_type(4))) unsigned short us4;

__device__ inline unsigned short f2bf(float f) {
    union { float f; unsigned int u; } x;
    x.f = f;
    unsigned int u = x.u;
    return (unsigned short)((u + 0x7FFF + ((u >> 16) & 1)) >> 16);
}
__device__ inline float bf2f(unsigned short u) {
    union { unsigned int u; float f; } x;
    x.u = (unsigned int)u << 16;
    return x.f;
}

// ---------------- edge-index dtype detection + normalization ----------------

__global__ void detect_k(const int* __restrict__ ei, int* __restrict__ flag) {
    __shared__ int any;
    if (threadIdx.x == 0) any = 0;
    __syncthreads();
    int v = 0;
    for (int r = 0; r < 4; r++) {
        int e = threadIdx.x + r * 256;
        v |= ei[e * 2 + 1];
    }
    if (v != 0) atomicOr(&any, 1);
    __syncthreads();
    if (threadIdx.x == 0) *flag = any;  // 1 => int32 layout, 0 => int64
}

__global__ void conv_k(const int* __restrict__ ei, const int* __restrict__ flag,
                       int* __restrict__ srcN, int* __restrict__ dstN, int E) {
    int e = blockIdx.x * 256 + threadIdx.x;
    if (e >= E) return;
    if (*flag) {
        srcN[e] = ei[e];
        dstN[e] = ei[E + e];
    } else {
        const long long* e64 = (const long long*)ei;
        srcN[e] = (int)e64[e];
        dstN[e] = (int)e64[E + e];
    }
}

// ---------------- CSR build ----------------

__global__ void hist_k(const int* __restrict__ dst, int* __restrict__ cnt, int E) {
    int e = blockIdx.x * 256 + threadIdx.x;
    if (e < E) atomicAdd(&cnt[dst[e]], 1);
}

__global__ void dinv_k(const int* __restrict__ cnt, float* __restrict__ dinv, int n) {
    int i = blockIdx.x * 256 + threadIdx.x;
    if (i < n) dinv[i] = rsqrtf((float)cnt[i] + 1.0f);
}

__global__ __launch_bounds__(256) void scan1_k(const int* __restrict__ cnt,
                                               int* __restrict__ bsum, int n) {
    int t = threadIdx.x;
    int i = blockIdx.x * 256 + t;
    int v = (i < n) ? cnt[i] : 0;
    for (int off = 32; off; off >>= 1) v += __shfl_down(v, off, 64);
    __shared__ int ws[4];
    if ((t & 63) == 0) ws[t >> 6] = v;
    __syncthreads();
    if (t == 0) bsum[blockIdx.x] = ws[0] + ws[1] + ws[2] + ws[3];
}

__global__ __launch_bounds__(256) void scan2_k(int* __restrict__ bsum,
                                               int* __restrict__ btot, int nb) {
    __shared__ int s[256];
    int t = threadIdx.x;
    int v = (t < nb) ? bsum[t] : 0;
    s[t] = v;
    __syncthreads();
    for (int off = 1; off < 256; off <<= 1) {
        int u = (t >= off) ? s[t - off] : 0;
        __syncthreads();
        s[t] += u;
        __syncthreads();
    }
    if (t < nb) bsum[t] = s[t] - v;  // exclusive
    if (t == nb - 1) *btot = s[t];   // rowptr[n]
}

__global__ __launch_bounds__(256) void scan3_k(const int* __restrict__ cnt,
                                               const int* __restrict__ bsum,
                                               int* __restrict__ rowptr,
                                               int* __restrict__ fill, int n) {
    __shared__ int s[256];
    int t = threadIdx.x;
    int i = blockIdx.x * 256 + t;
    int v = (i < n) ? cnt[i] : 0;
    s[t] = v;
    __syncthreads();
    for (int off = 1; off < 256; off <<= 1) {
        int u = (t >= off) ? s[t - off] : 0;
        __syncthreads();
        s[t] += u;
        __syncthreads();
    }
    if (i < n) {
        int excl = s[t] - v + bsum[blockIdx.x];
        rowptr[i] = excl;
        fill[i] = excl;
    }
}

__global__ void scatter_k(const int* __restrict__ srcI, const int* __restrict__ dstI,
                          int* __restrict__ fill, int* __restrict__ csr_src,
                          float* __restrict__ csr_w, const float* __restrict__ dinv, int E) {
    int e = blockIdx.x * 256 + threadIdx.x;
    if (e >= E) return;
    int s = srcI[e], d = dstI[e];
    int pos = atomicAdd(&fill[d], 1);
    csr_src[pos] = s;
    csr_w[pos] = dinv[s] * dinv[d];
}

// ---------------- weight packing (bf16, B-fragment layout) ------------------
// Bp layout: [K/32][Mp][32]; frag addr = col*32 + kq*8.

__global__ void pack1b_k(const float* __restrict__ w0, const float* __restrict__ w1,
                         const float* __restrict__ w2, unsigned short* __restrict__ Bp) {
    int idx = blockIdx.x * 256 + threadIdx.x;
    if (idx >= (F_IN / 32) * L1W * 32) return;
    int kk = idx & 31;
    int nn = (idx >> 5) % L1W;
    int kt = idx / (L1W * 32);
    int k = kt * 32 + kk;
    int p = nn >> 7, c = nn & 127;
    const float* w = (p == 0) ? w0 : (p == 1) ? w1 : w2;
    Bp[idx] = f2bf(w[k * H1 + c]);
}

__global__ void pack2b_k(const float* __restrict__ w0, const float* __restrict__ w1,
                         const float* __restrict__ w2, unsigned short* __restrict__ Bp) {
    int idx = blockIdx.x * 256 + threadIdx.x;
    if (idx >= (L1W / 32) * L2WP * 32) return;
    int kk = idx & 31;
    int nn = (idx >> 5) & (L2WP - 1);
    int kt = idx >> 12;  // 128*32 = 4096
    int k = kt * 32 + kk;
    unsigned short v = 0;
    if (nn < L2W) {
        int p = nn / 40, c = nn % 40;
        const float* w = (p == 0) ? w0 : (p == 1) ? w1 : w2;
        v = f2bf(w[k * C_OUT + c]);
    }
    Bp[idx] = v;
}

// ---------------- layer-1 GEMM: fused cvt + bias/relu epilogue --------------
// A fp32 [N x 256] (converted to bf16 on the fly). Wave = 16 rows x 384 cols
// (24 MFMAs per A-frag load). Output: cols 0:128 -> relu(+b1) -> Hb[:,0:128];
// cols 128:384 raw bf16 -> Y2b[N x 256]. One block = 64 rows, all cols.

__global__ __launch_bounds__(256) void mgemm1_k(const float* __restrict__ A,
                                                const unsigned short* __restrict__ Bp,
                                                const float* __restrict__ b1,
                                                unsigned short* __restrict__ Hb,
                                                unsigned short* __restrict__ Y2b, int N) {
    int wave = threadIdx.x >> 6, lane = threadIdx.x & 63;
    int m = lane & 15, kq = lane >> 4;
    int row0 = blockIdx.x * 64 + wave * 16;
    int arow = row0 + m;
    if (arow >= N) arow = N - 1;  // clamped duplicate; stores guarded
    const float* Ap = A + (size_t)arow * F_IN + kq * 8;
    size_t bbase = (size_t)m * 32 + kq * 8;
    f32x4 acc[24];
#pragma unroll
    for (int s = 0; s < 24; s++) acc[s] = (f32x4){0.f, 0.f, 0.f, 0.f};
    for (int kt = 0; kt < F_IN / 32; kt++) {
        float4 af0 = *(const float4*)(Ap + kt * 32);
        float4 af1 = *(const float4*)(Ap + kt * 32 + 4);
        short8 a;
        a[0] = (short)f2bf(af0.x); a[1] = (short)f2bf(af0.y);
        a[2] = (short)f2bf(af0.z); a[3] = (short)f2bf(af0.w);
        a[4] = (short)f2bf(af1.x); a[5] = (short)f2bf(af1.y);
        a[6] = (short)f2bf(af1.z); a[7] = (short)f2bf(af1.w);
        const unsigned short* Bkt = Bp + (size_t)kt * L1W * 32;
#pragma unroll
        for (int g = 0; g < 6; g++) {
            const unsigned short* Bg = Bkt + g * (64 * 32) + bbase;
            short8 b0 = *(const short8*)(Bg);
            short8 b1v = *(const short8*)(Bg + 16 * 32);
            short8 b2v = *(const short8*)(Bg + 32 * 32);
            short8 b3v = *(const short8*)(Bg + 48 * 32);
            acc[g * 4 + 0] = __builtin_amdgcn_mfma_f32_16x16x32_bf16(a, b0, acc[g * 4 + 0], 0, 0, 0);
            acc[g * 4 + 1] = __builtin_amdgcn_mfma_f32_16x16x32_bf16(a, b1v, acc[g * 4 + 1], 0, 0, 0);
            acc[g * 4 + 2] = __builtin_amdgcn_mfma_f32_16x16x32_bf16(a, b2v, acc[g * 4 + 2], 0, 0, 0);
            acc[g * 4 + 3] = __builtin_amdgcn_mfma_f32_16x16x32_bf16(a, b3v, acc[g * 4 + 3], 0, 0, 0);
        }
    }
    // C/D: col = s*16 + m, row = crow + r
    int crow = row0 + kq * 4;
#pragma unroll
    for (int s = 0; s < 24; s++) {
        int col = s * 16 + m;
        float bias = (col < 128) ? b1[col] : 0.f;
#pragma unroll
        for (int r = 0; r < 4; r++) {
            int row = crow + r;
            if (row < N) {
                float v = acc[s][r];
                if (col < 128) Hb[(size_t)row * L1W + col] = f2bf(fmaxf(v + bias, 0.f));
                else Y2b[(size_t)row * 256 + (col - 128)] = f2bf(v);
            }
        }
    }
}

// ---------------- layer-2 GEMM: bf16 out ------------------------------------
// A = Hb bf16 [N x 384]; wave = 16 rows x 128 cols; out Ub bf16 [N x 128].

__global__ __launch_bounds__(256) void mgemm2_k(const unsigned short* __restrict__ A,
                                                const unsigned short* __restrict__ Bp,
                                                unsigned short* __restrict__ Ub, int N) {
    int wave = threadIdx.x >> 6, lane = threadIdx.x & 63;
    int m = lane & 15, kq = lane >> 4;
    int row0 = blockIdx.x * 64 + wave * 16;
    int arow = row0 + m;
    if (arow >= N) arow = N - 1;
    const unsigned short* Ap = A + (size_t)arow * L1W + kq * 8;
    size_t bbase = (size_t)m * 32 + kq * 8;
    f32x4 acc[8];
#pragma unroll
    for (int s = 0; s < 8; s++) acc[s] = (f32x4){0.f, 0.f, 0.f, 0.f};
    for (int kt = 0; kt < L1W / 32; kt++) {
        short8 a = *(const short8*)(Ap + kt * 32);
        const unsigned short* Bkt = Bp + (size_t)kt * L2WP * 32 + bbase;
#pragma unroll
        for (int s = 0; s < 8; s++) {
            short8 b = *(const short8*)(Bkt + s * (16 * 32));
            acc[s] = __builtin_amdgcn_mfma_f32_16x16x32_bf16(a, b, acc[s], 0, 0, 0);
        }
    }
    int crow = row0 + kq * 4;
#pragma unroll
    for (int s = 0; s < 8; s++) {
        int col = s * 16 + m;
#pragma unroll
        for (int r = 0; r < 4; r++) {
            int row = crow + r;
            if (row < N) Ub[(size_t)row * L2WP + col] = f2bf(acc[s][r]);
        }
    }
}

// ---------------- fused width-256 bf16 prop over Y2b ------------------------
// lanes 0..31: z1 = P(y1) -> relu(+b1) -> Hb[:,128:256]
// lanes 32..63: t = P(y2) -> raw -> Tb[N x 128]

__global__ __launch_bounds__(256) void prop256b_k(const unsigned short* __restrict__ Y2b,
                                                  unsigned short* __restrict__ Hb,
                                                  unsigned short* __restrict__ Tb,
                                                  const int* __restrict__ rowptr,
                                                  const int* __restrict__ csr_src,
                                                  const float* __restrict__ csr_w,
                                                  const float* __restrict__ dinv,
                                                  const float* __restrict__ b1, int n) {
    int wave = threadIdx.x >> 6, lane = threadIdx.x & 63;
    int i = blockIdx.x * 4 + wave;
    if (i >= n) return;
    int beg = rowptr[i], end = rowptr[i + 1];
    float di = dinv[i];
    const unsigned short* sbase = Y2b + (size_t)lane * 4;
    us4 sv = *(const us4*)(sbase + (size_t)i * 256);
    float w = di * di;
    float a0 = w * bf2f(sv.x), a1 = w * bf2f(sv.y), a2 = w * bf2f(sv.z), a3 = w * bf2f(sv.w);
    int k = beg;
    for (; k + 3 < end; k += 4) {
        int i0 = csr_src[k], i1 = csr_src[k + 1], i2 = csr_src[k + 2], i3 = csr_src[k + 3];
        float w0 = csr_w[k], w1 = csr_w[k + 1], w2 = csr_w[k + 2], w3 = csr_w[k + 3];
        us4 v0 = *(const us4*)(sbase + (size_t)i0 * 256);
        us4 v1 = *(const us4*)(sbase + (size_t)i1 * 256);
        us4 v2 = *(const us4*)(sbase + (size_t)i2 * 256);
        us4 v3 = *(const us4*)(sbase + (size_t)i3 * 256);
        a0 = fmaf(w0, bf2f(v0.x), a0); a1 = fmaf(w0, bf2f(v0.y), a1);
        a2 = fmaf(w0, bf2f(v0.z), a2); a3 = fmaf(w0, bf2f(v0.w), a3);
        a0 = fmaf(w1, bf2f(v1.x), a0); a1 = fmaf(w1, bf2f(v1.y), a1);
        a2 = fmaf(w1, bf2f(v1.z), a2); a3 = fmaf(w1, bf2f(v1.w), a3);
        a0 = fmaf(w2, bf2f(v2.x), a0); a1 = fmaf(w2, bf2f(v2.y), a1);
        a2 = fmaf(w2, bf2f(v2.z), a2); a3 = fmaf(w2, bf2f(v2.w), a3);
        a0 = fmaf(w3, bf2f(v3.x), a0); a1 = fmaf(w3, bf2f(v3.y), a1);
        a2 = fmaf(w3, bf2f(v3.z), a2); a3 = fmaf(w3, bf2f(v3.w), a3);
    }
    for (; k < end; k++) {
        int i0 = csr_src[k];
        float w0 = csr_w[k];
        us4 v0 = *(const us4*)(sbase + (size_t)i0 * 256);
        a0 = fmaf(w0, bf2f(v0.x), a0); a1 = fmaf(w0, bf2f(v0.y), a1);
        a2 = fmaf(w0, bf2f(v0.z), a2); a3 = fmaf(w0, bf2f(v0.w), a3);
    }
    int c = lane * 4;
    us4 o;
    if (c < 128) {  // z1 -> h cols 128..255, bias+relu
        const float4 b = *(const float4*)(b1 + 128 + c);
        o.x = f2bf(fmaxf(a0 + b.x, 0.f));
        o.y = f2bf(fmaxf(a1 + b.y, 0.f));
        o.z = f2bf(fmaxf(a2 + b.z, 0.f));
        o.w = f2bf(fmaxf(a3 + b.w, 0.f));
        *(us4*)(Hb + (size_t)i * L1W + 128 + c) = o;
    } else {        // t -> Tb
        o.x = f2bf(a0); o.y = f2bf(a1); o.z = f2bf(a2); o.w = f2bf(a3);
        *(us4*)(Tb + (size_t)i * 128 + (c - 128)) = o;
    }
}

// ---------------- width-128 bf16 prop: Hb[:,256:384] = relu(P(Tb)+b1) -------

__global__ __launch_bounds__(256) void prop128b_k(const unsigned short* __restrict__ Tb,
                                                  unsigned short* __restrict__ Hb,
                                                  const int* __restrict__ rowptr,
                                                  const int* __restrict__ csr_src,
                                                  const float* __restrict__ csr_w,
                                                  const float* __restrict__ dinv,
                                                  const float* __restrict__ b1, int n) {
    int wave = threadIdx.x >> 6, lane = threadIdx.x & 63;
    int i = blockIdx.x * 4 + wave;
    if (i >= n) return;
    int beg = rowptr[i], end = rowptr[i + 1];
    float di = dinv[i];
    const unsigned int* sbase = (const unsigned int*)Tb + lane;
    unsigned int sv = sbase[(size_t)i * 64];
    float w = di * di;
    float a0 = w * bf2f((unsigned short)sv), a1 = w * bf2f((unsigned short)(sv >> 16));
    int k = beg;
    for (; k + 3 < end; k += 4) {
        int i0 = csr_src[k], i1 = csr_src[k + 1], i2 = csr_src[k + 2], i3 = csr_src[k + 3];
        float w0 = csr_w[k], w1 = csr_w[k + 1], w2 = csr_w[k + 2], w3 = csr_w[k + 3];
        unsigned int v0 = sbase[(size_t)i0 * 64];
        unsigned int v1 = sbase[(size_t)i1 * 64];
        unsigned int v2 = sbase[(size_t)i2 * 64];
        unsigned int v3 = sbase[(size_t)i3 * 64];
        a0 = fmaf(w0, bf2f((unsigned short)v0), a0); a1 = fmaf(w0, bf2f((unsigned short)(v0 >> 16)), a1);
        a0 = fmaf(w1, bf2f((unsigned short)v1), a0); a1 = fmaf(w1, bf2f((unsigned short)(v1 >> 16)), a1);
        a0 = fmaf(w2, bf2f((unsigned short)v2), a0); a1 = fmaf(w2, bf2f((unsigned short)(v2 >> 16)), a1);
        a0 = fmaf(w3, bf2f((unsigned short)v3), a0); a1 = fmaf(w3, bf2f((unsigned short)(v3 >> 16)), a1);
    }
    for (; k < end; k++) {
        int i0 = csr_src[k];
        float w0 = csr_w[k];
        unsigned int v0 = sbase[(size_t)i0 * 64];
        a0 = fmaf(w0, bf2f((unsigned short)v0), a0); a1 = fmaf(w0, bf2f((unsigned short)(v0 >> 16)), a1);
    }
    int c = lane * 2;  // h col 256+c
    float r0 = fmaxf(a0 + b1[256 + c], 0.f);
    float r1 = fmaxf(a1 + b1[256 + c + 1], 0.f);
    unsigned int o = (unsigned int)f2bf(r0) | ((unsigned int)f2bf(r1) << 16);
    *((unsigned int*)(Hb + (size_t)i * L1W + 256) + lane) = o;
}

// ---------------- fused width-80 bf16 prop (layer 2) ------------------------
// gathers Ub cols 40:120; lanes 0..19 -> T2a (v1), 20..39 -> T2b (t2)

__global__ __launch_bounds__(256) void prop80b_k(const unsigned short* __restrict__ Ub,
                                                 unsigned short* __restrict__ T2a,
                                                 unsigned short* __restrict__ T2b,
                                                 const int* __restrict__ rowptr,
                                                 const int* __restrict__ csr_src,
                                                 const float* __restrict__ csr_w,
                                                 const float* __restrict__ dinv, int n) {
    int wave = threadIdx.x >> 6, lane = threadIdx.x & 63;
    int i = blockIdx.x * 4 + wave;
    if (i >= n) return;
    int beg = rowptr[i], end = rowptr[i + 1];
    float di = dinv[i];
    bool act = lane < 40;
    const unsigned int* sbase = (const unsigned int*)(Ub + 40) + lane;
    float a0 = 0.f, a1 = 0.f;
    if (act) {
        unsigned int sv = sbase[(size_t)i * 64];
        float w = di * di;
        a0 = w * bf2f((unsigned short)sv); a1 = w * bf2f((unsigned short)(sv >> 16));
    }
    int k = beg;
    for (; k + 1 < end; k += 2) {
        int i0 = csr_src[k], i1 = csr_src[k + 1];
        float w0 = csr_w[k], w1 = csr_w[k + 1];
        if (act) {
            unsigned int v0 = sbase[(size_t)i0 * 64];
            unsigned int v1 = sbase[(size_t)i1 * 64];
            a0 = fmaf(w0, bf2f((unsigned short)v0), a0); a1 = fmaf(w0, bf2f((unsigned short)(v0 >> 16)), a1);
            a0 = fmaf(w1, bf2f((unsigned short)v1), a0); a1 = fmaf(w1, bf2f((unsigned short)(v1 >> 16)), a1);
        }
    }
    if (k < end) {
        int i0 = csr_src[k];
        float w0 = csr_w[k];
        if (act) {
            unsigned int v0 = sbase[(size_t)i0 * 64];
            a0 = fmaf(w0, bf2f((unsigned short)v0), a0); a1 = fmaf(w0, bf2f((unsigned short)(v0 >> 16)), a1);
        }
    }
    if (act) {
        unsigned int o = (unsigned int)f2bf(a0) | ((unsigned int)f2bf(a1) << 16);
        if (lane < 20) *((unsigned int*)T2a + (size_t)i * 20 + lane) = o;
        else *((unsigned int*)T2b + (size_t)i * 20 + (lane - 20)) = o;
    }
}

// ---------------- width-40 bf16 prop (2nd hop): Ub[:,80:120] = P(T2b) -------

__global__ __launch_bounds__(256) void prop40b_k(const unsigned short* __restrict__ T2b,
                                                 unsigned short* __restrict__ Ub,
                                                 const int* __restrict__ rowptr,
                                                 const int* __restrict__ csr_src,
                                                 const float* __restrict__ csr_w,
                                                 const float* __restrict__ dinv, int n) {
    int wave = threadIdx.x >> 6, lane = threadIdx.x & 63;
    int i = blockIdx.x * 4 + wave;
    if (i >= n) return;
    int beg = rowptr[i], end = rowptr[i + 1];
    float di = dinv[i];
    bool act = lane < 20;
    const unsigned int* sbase = (const unsigned int*)T2b + lane;
    float a0 = 0.f, a1 = 0.f;
    if (act) {
        unsigned int sv = sbase[(size_t)i * 20];
        float w = di * di;
        a0 = w * bf2f((unsigned short)sv); a1 = w * bf2f((unsigned short)(sv >> 16));
    }
    int k = beg;
    for (; k + 1 < end; k += 2) {
        int i0 = csr_src[k], i1 = csr_src[k + 1];
        float w0 = csr_w[k], w1 = csr_w[k + 1];
        if (act) {
            unsigned int v0 = sbase[(size_t)i0 * 20];
            unsigned int v1 = sbase[(size_t)i1 * 20];
            a0 = fmaf(w0, bf2f((unsigned short)v0), a0); a1 = fmaf(w0, bf2f((unsigned short)(v0 >> 16)), a1);
            a0 = fmaf(w1, bf2f((unsigned short)v1), a0); a1 = fmaf(w1, bf2f((unsigned short)(v1 >> 16)), a1);
        }
    }
    if (k < end) {
        int i0 = csr_src[k];
        float w0 = csr_w[k];
        if (act) {
            unsigned int v0 = sbase[(size_t)i0 * 20];
            a0 = fmaf(w0, bf2f((unsigned short)v0), a0); a1 = fmaf(w0, bf2f((unsigned short)(v0 >> 16)), a1);
        }
    }
    if (act) {
        unsigned int o = (unsigned int)f2bf(a0) | ((unsigned int)f2bf(a1) << 16);
        *((unsigned int*)Ub + (size_t)i * 64 + 40 + lane) = o;
    }
}

// ---------------- log_softmax epilogue (bf16 logits) ------------------------
// col j: j<40 -> Ub[i,j]; 40<=j<80 -> T2a[i,j-40]; 80<=j<120 -> Ub[i,j]; +b2[j]

__global__ __launch_bounds__(256) void lsm_k(const unsigned short* __restrict__ Ub,
                                             const unsigned short* __restrict__ T2a,
                                             const float* __restrict__ b2,
                                             float* __restrict__ out, int n) {
    int wave = threadIdx.x >> 6;
    int lane = threadIdx.x & 63;
    int i = blockIdx.x * 4 + wave;
    if (i >= n) return;
    float v0, v1;
    {
        int j = lane;  // 0..63
        float v = (j >= 40) ? bf2f(T2a[(size_t)i * 40 + (j - 40)]) : bf2f(Ub[(size_t)i * L2WP + j]);
        v0 = v + b2[j];
    }
    if (lane + 64 < 120) {
        int j = lane + 64;  // 64..119
        float v = (j < 80) ? bf2f(T2a[(size_t)i * 40 + (j - 40)]) : bf2f(Ub[(size_t)i * L2WP + j]);
        v1 = v + b2[j];
    } else {
        v1 = -INFINITY;
    }
    float m = fmaxf(v0, v1);
    for (int off = 32; off; off >>= 1) m = fmaxf(m, __shfl_xor(m, off, 64));
    float s = expf(v0 - m) + ((lane + 64 < 120) ? expf(v1 - m) : 0.f);
    for (int off = 32; off; off >>= 1) s += __shfl_xor(s, off, 64);
    float ls = logf(s) + m;
    out[(size_t)i * 120 + lane] = v0 - ls;
    if (lane + 64 < 120) out[(size_t)i * 120 + lane + 64] = v1 - ls;
}

// ---------------- launch ----------------

static inline size_t align256(size_t x) { return (x + 255) & ~(size_t)255; }

extern "C" void kernel_launch(void* const* d_in, const int* in_sizes, int n_in,
                              void* d_out, int out_size, void* d_ws, size_t ws_size,
                              hipStream_t stream) {
    const float* x = (const float*)d_in[0];
    const int* ei = (const int*)d_in[1];
    const float* W1_0 = (const float*)d_in[2];
    const float* W1_1 = (const float*)d_in[3];
    const float* W1_2 = (const float*)d_in[4];
    const float* b1 = (const float*)d_in[5];
    const float* W2_0 = (const float*)d_in[6];
    const float* W2_1 = (const float*)d_in[7];
    const float* W2_2 = (const float*)d_in[8];
    const float* b2 = (const float*)d_in[9];
    float* out = (float*)d_out;

    const int n = N_NODES;
    const int E = in_sizes[1] / 2;
    const int nb = (n + 255) / 256;

    char* p = (char*)d_ws;
    size_t off = 0;
    auto alloc = [&](size_t bytes) {
        void* r = p + off;
        off = align256(off + bytes);
        return r;
    };
    int* flag = (int*)alloc(4);
    int* srcN = (int*)alloc((size_t)E * 4);
    int* dstN = (int*)alloc((size_t)E * 4);
    int* cnt = (int*)alloc((size_t)n * 4);
    int* rowptr = (int*)alloc((size_t)(n + 1) * 4);
    int* fill = (int*)alloc((size_t)n * 4);
    int* bsum = (int*)alloc((size_t)nb * 4);
    float* dinv = (float*)alloc((size_t)n * 4);
    int* csr_src = (int*)alloc((size_t)E * 4);
    float* csr_w = (float*)alloc((size_t)E * 4);
    unsigned short* Bp1 = (unsigned short*)alloc((size_t)(F_IN / 32) * L1W * 32 * 2);
    unsigned short* Bp2 = (unsigned short*)alloc((size_t)(L1W / 32) * L2WP * 32 * 2);
    unsigned short* Hb = (unsigned short*)alloc((size_t)n * L1W * 2);
    unsigned short* Y2b = (unsigned short*)alloc((size_t)n * 256 * 2);
    unsigned short* Tb = (unsigned short*)alloc((size_t)n * 128 * 2);
    unsigned short* Ub = (unsigned short*)alloc((size_t)n * L2WP * 2);
    unsigned short* T2a = (unsigned short*)alloc((size_t)n * C_OUT * 2);
    unsigned short* T2b = (unsigned short*)alloc((size_t)n * C_OUT * 2);
    (void)ws_size;

    // 0. edge dtype normalize
    detect_k<<<1, 256, 0, stream>>>(ei, flag);
    conv_k<<<(E + 255) / 256, 256, 0, stream>>>(ei, flag, srcN, dstN, E);

    // 1. CSR build
    hipMemsetAsync(cnt, 0, (size_t)n * 4, stream);
    hist_k<<<(E + 255) / 256, 256, 0, stream>>>(dstN, cnt, E);
    dinv_k<<<(n + 255) / 256, 256, 0, stream>>>(cnt, dinv, n);
    scan1_k<<<nb, 256, 0, stream>>>(cnt, bsum, n);
    scan2_k<<<1, 256, 0, stream>>>(bsum, rowptr + n, nb);
    scan3_k<<<nb, 256, 0, stream>>>(cnt, bsum, rowptr, fill, n);
    scatter_k<<<(E + 255) / 256, 256, 0, stream>>>(srcN, dstN, fill, csr_src, csr_w, dinv, E);

    // 2. weight packing
    pack1b_k<<<((F_IN / 32) * L1W * 32 + 255) / 256, 256, 0, stream>>>(W1_0, W1_1, W1_2, Bp1);
    pack2b_k<<<((L1W / 32) * L2WP * 32 + 255) / 256, 256, 0, stream>>>(W2_0, W2_1, W2_2, Bp2);

    // 3. layer 1 GEMM (fused cvt + bias/relu split store)
    mgemm1_k<<<(n + 63) / 64, 256, 0, stream>>>(x, Bp1, b1, Hb, Y2b, n);
    // fused prop: Hb[:,128:256] = relu(P(y1)+b1), Tb = P(y2)
    prop256b_k<<<(n + 3) / 4, 256, 0, stream>>>(Y2b, Hb, Tb, rowptr, csr_src, csr_w, dinv, b1, n);
    // Hb[:,256:384] = relu(P(Tb)+b1)
    prop128b_k<<<(n + 3) / 4, 256, 0, stream>>>(Tb, Hb, rowptr, csr_src, csr_w, dinv, b1, n);

    // 4. layer 2 GEMM -> bf16 Ub
    mgemm2_k<<<(n + 63) / 64, 256, 0, stream>>>(Hb, Bp2, Ub, n);
    // fused: T2a = P(u1), T2b = P(u2)
    prop80b_k<<<(n + 3) / 4, 256, 0, stream>>>(Ub, T2a, T2b, rowptr, csr_src, csr_w, dinv, n);
    // second hop: Ub[:,80:120] = P(T2b)
    prop40b_k<<<(n + 3) / 4, 256, 0, stream>>>(T2b, Ub, rowptr, csr_src, csr_w, dinv, n);

    // 5. log_softmax epilogue
    lsm_k<<<(n + 3) / 4, 256, 0, stream>>>(Ub, T2a, b2, out, n);
}

// Round 8
// 521.909 us; speedup vs baseline: 1.0168x; 1.0168x over previous
//
#include <hip/hip_runtime.h>
#include <hip/hip_bf16.h>
#include <math.h>

#define N_NODES 50000
#define F_IN 256
#define H1 128
#define C_OUT 40
#define L1W 384   // 3*H1
#define L2W 120   // 3*C_OUT
#define L2WP 128  // padded

typedef __attribute__((ext_vector_type(8))) short short8;
typedef __attribute__((ext_vector_type(4))) float f32x4;
typedef __attribute__((ext_vector_type(4))) unsigned short us4;

__device__ inline unsigned short f2bf(float f) {
    union { float f; unsigned int u; } x;
    x.f = f;
    unsigned int u = x.u;
    return (unsigned short)((u + 0x7FFF + ((u >> 16) & 1)) >> 16);
}
__device__ inline float bf2f(unsigned short u) {
    union { unsigned int u; float f; } x;
    x.u = (unsigned int)u << 16;
    return x.f;
}

// ---------------- edge-index dtype detection + normalization ----------------

__global__ void detect_k(const int* __restrict__ ei, int* __restrict__ flag) {
    __shared__ int any;
    if (threadIdx.x == 0) any = 0;
    __syncthreads();
    int v = 0;
    for (int r = 0; r < 4; r++) {
        int e = threadIdx.x + r * 256;
        v |= ei[e * 2 + 1];
    }
    if (v != 0) atomicOr(&any, 1);
    __syncthreads();
    if (threadIdx.x == 0) *flag = any;  // 1 => int32 layout, 0 => int64
}

__global__ void conv_k(const int* __restrict__ ei, const int* __restrict__ flag,
                       int* __restrict__ srcN, int* __restrict__ dstN, int E) {
    int e = blockIdx.x * 256 + threadIdx.x;
    if (e >= E) return;
    if (*flag) {
        srcN[e] = ei[e];
        dstN[e] = ei[E + e];
    } else {
        const long long* e64 = (const long long*)ei;
        srcN[e] = (int)e64[e];
        dstN[e] = (int)e64[E + e];
    }
}

// ---------------- CSR build ----------------

__global__ void hist_k(const int* __restrict__ dst, int* __restrict__ cnt, int E) {
    int e = blockIdx.x * 256 + threadIdx.x;
    if (e < E) atomicAdd(&cnt[dst[e]], 1);
}

__global__ void dinv_k(const int* __restrict__ cnt, float* __restrict__ dinv, int n) {
    int i = blockIdx.x * 256 + threadIdx.x;
    if (i < n) dinv[i] = rsqrtf((float)cnt[i] + 1.0f);
}

__global__ __launch_bounds__(256) void scan1_k(const int* __restrict__ cnt,
                                               int* __restrict__ bsum, int n) {
    int t = threadIdx.x;
    int i = blockIdx.x * 256 + t;
    int v = (i < n) ? cnt[i] : 0;
    for (int off = 32; off; off >>= 1) v += __shfl_down(v, off, 64);
    __shared__ int ws[4];
    if ((t & 63) == 0) ws[t >> 6] = v;
    __syncthreads();
    if (t == 0) bsum[blockIdx.x] = ws[0] + ws[1] + ws[2] + ws[3];
}

__global__ __launch_bounds__(256) void scan2_k(int* __restrict__ bsum,
                                               int* __restrict__ btot, int nb) {
    __shared__ int s[256];
    int t = threadIdx.x;
    int v = (t < nb) ? bsum[t] : 0;
    s[t] = v;
    __syncthreads();
    for (int off = 1; off < 256; off <<= 1) {
        int u = (t >= off) ? s[t - off] : 0;
        __syncthreads();
        s[t] += u;
        __syncthreads();
    }
    if (t < nb) bsum[t] = s[t] - v;  // exclusive
    if (t == nb - 1) *btot = s[t];   // rowptr[n]
}

__global__ __launch_bounds__(256) void scan3_k(const int* __restrict__ cnt,
                                               const int* __restrict__ bsum,
                                               int* __restrict__ rowptr,
                                               int* __restrict__ fill, int n) {
    __shared__ int s[256];
    int t = threadIdx.x;
    int i = blockIdx.x * 256 + t;
    int v = (i < n) ? cnt[i] : 0;
    s[t] = v;
    __syncthreads();
    for (int off = 1; off < 256; off <<= 1) {
        int u = (t >= off) ? s[t - off] : 0;
        __syncthreads();
        s[t] += u;
        __syncthreads();
    }
    if (i < n) {
        int excl = s[t] - v + bsum[blockIdx.x];
        rowptr[i] = excl;
        fill[i] = excl;
    }
}

__global__ void scatter_k(const int* __restrict__ srcI, const int* __restrict__ dstI,
                          int* __restrict__ fill, int* __restrict__ csr_src,
                          float* __restrict__ csr_w, const float* __restrict__ dinv, int E) {
    int e = blockIdx.x * 256 + threadIdx.x;
    if (e >= E) return;
    int s = srcI[e], d = dstI[e];
    int pos = atomicAdd(&fill[d], 1);
    csr_src[pos] = s;
    csr_w[pos] = dinv[s] * dinv[d];
}

// ---------------- weight packing (bf16, B-fragment layout) ------------------
// Bp layout: [K/32][Mp][32]; frag addr = col*32 + kq*8.

__global__ void pack1b_k(const float* __restrict__ w0, const float* __restrict__ w1,
                         const float* __restrict__ w2, unsigned short* __restrict__ Bp) {
    int idx = blockIdx.x * 256 + threadIdx.x;
    if (idx >= (F_IN / 32) * L1W * 32) return;
    int kk = idx & 31;
    int nn = (idx >> 5) % L1W;
    int kt = idx / (L1W * 32);
    int k = kt * 32 + kk;
    int p = nn >> 7, c = nn & 127;
    const float* w = (p == 0) ? w0 : (p == 1) ? w1 : w2;
    Bp[idx] = f2bf(w[k * H1 + c]);
}

__global__ void pack2b_k(const float* __restrict__ w0, const float* __restrict__ w1,
                         const float* __restrict__ w2, unsigned short* __restrict__ Bp) {
    int idx = blockIdx.x * 256 + threadIdx.x;
    if (idx >= (L1W / 32) * L2WP * 32) return;
    int kk = idx & 31;
    int nn = (idx >> 5) & (L2WP - 1);
    int kt = idx >> 12;  // 128*32 = 4096
    int k = kt * 32 + kk;
    unsigned short v = 0;
    if (nn < L2W) {
        int p = nn / 40, c = nn % 40;
        const float* w = (p == 0) ? w0 : (p == 1) ? w1 : w2;
        v = f2bf(w[k * C_OUT + c]);
    }
    Bp[idx] = v;
}

// ---------------- layer-1 GEMM: LDS-staged B, fused cvt + bias/relu ---------
// Block = 64 rows x 384 cols, 4 waves (wave = 16 rows x 384 cols, 24 accs).
// B tile (384x32 bf16 = 24 KB) double-buffered in LDS, XOR-swizzled 16B chunks:
// chunk (col, p) lives at byte col*64 + (p ^ ((col>>1)&3))*16  -> <=2-way banks.

__global__ __launch_bounds__(256, 3) void mgemm1_k(const float* __restrict__ A,
                                                   const unsigned short* __restrict__ Bp,
                                                   const float* __restrict__ b1,
                                                   unsigned short* __restrict__ Hb,
                                                   unsigned short* __restrict__ Y2b, int N) {
    __shared__ unsigned short Bs[2][L1W * 32];  // 2 x 24576 B
    int tid = threadIdx.x;
    int wave = tid >> 6, lane = tid & 63;
    int m = lane & 15, kq = lane >> 4;
    int row0 = blockIdx.x * 64 + wave * 16;
    int arow = row0 + m;
    if (arow >= N) arow = N - 1;  // clamped duplicate; stores guarded
    const float* Ap = A + (size_t)arow * F_IN + kq * 8;

    f32x4 acc[24];
#pragma unroll
    for (int s = 0; s < 24; s++) acc[s] = (f32x4){0.f, 0.f, 0.f, 0.f};

    short8 breg[6];
    float4 af0, af1;
    // preload kt=0
#pragma unroll
    for (int c = 0; c < 6; c++) {
        int t = tid + c * 256;
        breg[c] = *(const short8*)(Bp + (size_t)t * 8);
    }
    af0 = *(const float4*)(Ap);
    af1 = *(const float4*)(Ap + 4);
#pragma unroll
    for (int c = 0; c < 6; c++) {
        int t = tid + c * 256;
        int col = t >> 2, pp = t & 3;
        *(short8*)(&Bs[0][col * 32 + ((pp ^ ((col >> 1) & 3)) << 3)]) = breg[c];
    }
    __syncthreads();

    for (int kt = 0; kt < F_IN / 32; kt++) {
        short8 a;
        a[0] = (short)f2bf(af0.x); a[1] = (short)f2bf(af0.y);
        a[2] = (short)f2bf(af0.z); a[3] = (short)f2bf(af0.w);
        a[4] = (short)f2bf(af1.x); a[5] = (short)f2bf(af1.y);
        a[6] = (short)f2bf(af1.z); a[7] = (short)f2bf(af1.w);
        if (kt < F_IN / 32 - 1) {
            const unsigned short* Bn = Bp + (size_t)(kt + 1) * L1W * 32;
#pragma unroll
            for (int c = 0; c < 6; c++) {
                int t = tid + c * 256;
                breg[c] = *(const short8*)(Bn + (size_t)t * 8);
            }
            af0 = *(const float4*)(Ap + (kt + 1) * 32);
            af1 = *(const float4*)(Ap + (kt + 1) * 32 + 4);
        }
        const unsigned short* Bbuf = Bs[kt & 1];
#pragma unroll
        for (int s = 0; s < 24; s++) {
            int col = s * 16 + m;
            short8 b = *(const short8*)(&Bbuf[col * 32 + ((kq ^ ((col >> 1) & 3)) << 3)]);
            acc[s] = __builtin_amdgcn_mfma_f32_16x16x32_bf16(a, b, acc[s], 0, 0, 0);
        }
        if (kt < F_IN / 32 - 1) {
            int nb = (kt + 1) & 1;
#pragma unroll
            for (int c = 0; c < 6; c++) {
                int t = tid + c * 256;
                int col = t >> 2, pp = t & 3;
                *(short8*)(&Bs[nb][col * 32 + ((pp ^ ((col >> 1) & 3)) << 3)]) = breg[c];
            }
        }
        __syncthreads();
    }
    // C/D: col = s*16 + m, row = crow + r
    int crow = row0 + kq * 4;
#pragma unroll
    for (int s = 0; s < 24; s++) {
        int col = s * 16 + m;
        float bias = (col < 128) ? b1[col] : 0.f;
#pragma unroll
        for (int r = 0; r < 4; r++) {
            int row = crow + r;
            if (row < N) {
                float v = acc[s][r];
                if (col < 128) Hb[(size_t)row * L1W + col] = f2bf(fmaxf(v + bias, 0.f));
                else Y2b[(size_t)row * 256 + (col - 128)] = f2bf(v);
            }
        }
    }
}

// ---------------- layer-2 GEMM: LDS-staged B, bf16 out ----------------------
// Block = 64 rows x 128 cols; wave = 16 x 128 (8 accs). B tile 128x32 = 8 KB.

__global__ __launch_bounds__(256) void mgemm2_k(const unsigned short* __restrict__ A,
                                                const unsigned short* __restrict__ Bp,
                                                unsigned short* __restrict__ Ub, int N) {
    __shared__ unsigned short Bs[2][L2WP * 32];  // 2 x 8192 B
    int tid = threadIdx.x;
    int wave = tid >> 6, lane = tid & 63;
    int m = lane & 15, kq = lane >> 4;
    int row0 = blockIdx.x * 64 + wave * 16;
    int arow = row0 + m;
    if (arow >= N) arow = N - 1;
    const unsigned short* Ap = A + (size_t)arow * L1W + kq * 8;

    f32x4 acc[8];
#pragma unroll
    for (int s = 0; s < 8; s++) acc[s] = (f32x4){0.f, 0.f, 0.f, 0.f};

    short8 breg[2];
    short8 areg;
#pragma unroll
    for (int c = 0; c < 2; c++) {
        int t = tid + c * 256;
        breg[c] = *(const short8*)(Bp + (size_t)t * 8);
    }
    areg = *(const short8*)(Ap);
#pragma unroll
    for (int c = 0; c < 2; c++) {
        int t = tid + c * 256;
        int col = t >> 2, pp = t & 3;
        *(short8*)(&Bs[0][col * 32 + ((pp ^ ((col >> 1) & 3)) << 3)]) = breg[c];
    }
    __syncthreads();

    for (int kt = 0; kt < L1W / 32; kt++) {
        short8 a = areg;
        if (kt < L1W / 32 - 1) {
            const unsigned short* Bn = Bp + (size_t)(kt + 1) * L2WP * 32;
#pragma unroll
            for (int c = 0; c < 2; c++) {
                int t = tid + c * 256;
                breg[c] = *(const short8*)(Bn + (size_t)t * 8);
            }
            areg = *(const short8*)(Ap + (kt + 1) * 32);
        }
        const unsigned short* Bbuf = Bs[kt & 1];
#pragma unroll
        for (int s = 0; s < 8; s++) {
            int col = s * 16 + m;
            short8 b = *(const short8*)(&Bbuf[col * 32 + ((kq ^ ((col >> 1) & 3)) << 3)]);
            acc[s] = __builtin_amdgcn_mfma_f32_16x16x32_bf16(a, b, acc[s], 0, 0, 0);
        }
        if (kt < L1W / 32 - 1) {
            int nb = (kt + 1) & 1;
#pragma unroll
            for (int c = 0; c < 2; c++) {
                int t = tid + c * 256;
                int col = t >> 2, pp = t & 3;
                *(short8*)(&Bs[nb][col * 32 + ((pp ^ ((col >> 1) & 3)) << 3)]) = breg[c];
            }
        }
        __syncthreads();
    }
    int crow = row0 + kq * 4;
#pragma unroll
    for (int s = 0; s < 8; s++) {
        int col = s * 16 + m;
#pragma unroll
        for (int r = 0; r < 4; r++) {
            int row = crow + r;
            if (row < N) Ub[(size_t)row * L2WP + col] = f2bf(acc[s][r]);
        }
    }
}

// ---------------- XCD-sliced width-256 prop over Y2b ------------------------
// 8 col-slices of 32; slice = blockIdx.x & 7 (round-robin -> one slice per XCD,
// per-XCD gather working set 3.2 MB fits 4 MB L2). 16 dst nodes/block,
// 16 threads/node, uint (2 bf16 cols) per lane.
// slices 0..3 (y1): z1 -> relu(+b1) -> Hb[:,128:256]; slices 4..7 (y2): -> Tb.

__global__ __launch_bounds__(256) void prop256s_k(const unsigned short* __restrict__ Y2b,
                                                  unsigned short* __restrict__ Hb,
                                                  unsigned short* __restrict__ Tb,
                                                  const int* __restrict__ rowptr,
                                                  const int* __restrict__ csr_src,
                                                  const float* __restrict__ csr_w,
                                                  const float* __restrict__ dinv,
                                                  const float* __restrict__ b1, int n) {
    int slice = blockIdx.x & 7;
    int chunk = blockIdx.x >> 3;
    int t = threadIdx.x;
    int g = t >> 4, l = t & 15;
    int i = chunk * 16 + g;
    if (i >= n) return;
    int beg = rowptr[i], end = rowptr[i + 1];
    float di = dinv[i];
    const unsigned int* sb = (const unsigned int*)Y2b + slice * 16 + l;
    unsigned int sv = sb[(size_t)i * 128];
    float w = di * di;
    float a0 = w * bf2f((unsigned short)sv);
    float a1 = w * bf2f((unsigned short)(sv >> 16));
    int k = beg;
    for (; k + 3 < end; k += 4) {
        int i0 = csr_src[k], i1 = csr_src[k + 1], i2 = csr_src[k + 2], i3 = csr_src[k + 3];
        float w0 = csr_w[k], w1 = csr_w[k + 1], w2 = csr_w[k + 2], w3 = csr_w[k + 3];
        unsigned int v0 = sb[(size_t)i0 * 128];
        unsigned int v1 = sb[(size_t)i1 * 128];
        unsigned int v2 = sb[(size_t)i2 * 128];
        unsigned int v3 = sb[(size_t)i3 * 128];
        a0 = fmaf(w0, bf2f((unsigned short)v0), a0); a1 = fmaf(w0, bf2f((unsigned short)(v0 >> 16)), a1);
        a0 = fmaf(w1, bf2f((unsigned short)v1), a0); a1 = fmaf(w1, bf2f((unsigned short)(v1 >> 16)), a1);
        a0 = fmaf(w2, bf2f((unsigned short)v2), a0); a1 = fmaf(w2, bf2f((unsigned short)(v2 >> 16)), a1);
        a0 = fmaf(w3, bf2f((unsigned short)v3), a0); a1 = fmaf(w3, bf2f((unsigned short)(v3 >> 16)), a1);
    }
    for (; k < end; k++) {
        int i0 = csr_src[k];
        float w0 = csr_w[k];
        unsigned int v0 = sb[(size_t)i0 * 128];
        a0 = fmaf(w0, bf2f((unsigned short)v0), a0); a1 = fmaf(w0, bf2f((unsigned short)(v0 >> 16)), a1);
    }
    int c = slice * 32 + l * 2;  // col in Y2b space (0..255)
    if (c < 128) {               // z1 -> Hb col 128+c with bias+relu
        float r0 = fmaxf(a0 + b1[128 + c], 0.f);
        float r1 = fmaxf(a1 + b1[128 + c + 1], 0.f);
        unsigned int o = (unsigned int)f2bf(r0) | ((unsigned int)f2bf(r1) << 16);
        ((unsigned int*)(Hb + (size_t)i * L1W + 128))[slice * 16 + l] = o;
    } else {                     // t -> Tb col c-128
        unsigned int o = (unsigned int)f2bf(a0) | ((unsigned int)f2bf(a1) << 16);
        ((unsigned int*)Tb)[(size_t)i * 64 + (slice - 4) * 16 + l] = o;
    }
}

// ---------------- XCD-sliced width-128 prop: Hb[:,256:384] = relu(P(Tb)+b1) -

__global__ __launch_bounds__(256) void prop128s_k(const unsigned short* __restrict__ Tb,
                                                  unsigned short* __restrict__ Hb,
                                                  const int* __restrict__ rowptr,
                                                  const int* __restrict__ csr_src,
                                                  const float* __restrict__ csr_w,
                                                  const float* __restrict__ dinv,
                                                  const float* __restrict__ b1, int n) {
    int slice = blockIdx.x & 3;
    int chunk = blockIdx.x >> 2;
    int t = threadIdx.x;
    int g = t >> 4, l = t & 15;
    int i = chunk * 16 + g;
    if (i >= n) return;
    int beg = rowptr[i], end = rowptr[i + 1];
    float di = dinv[i];
    const unsigned int* sb = (const unsigned int*)Tb + slice * 16 + l;
    unsigned int sv = sb[(size_t)i * 64];
    float w = di * di;
    float a0 = w * bf2f((unsigned short)sv);
    float a1 = w * bf2f((unsigned short)(sv >> 16));
    int k = beg;
    for (; k + 3 < end; k += 4) {
        int i0 = csr_src[k], i1 = csr_src[k + 1], i2 = csr_src[k + 2], i3 = csr_src[k + 3];
        float w0 = csr_w[k], w1 = csr_w[k + 1], w2 = csr_w[k + 2], w3 = csr_w[k + 3];
        unsigned int v0 = sb[(size_t)i0 * 64];
        unsigned int v1 = sb[(size_t)i1 * 64];
        unsigned int v2 = sb[(size_t)i2 * 64];
        unsigned int v3 = sb[(size_t)i3 * 64];
        a0 = fmaf(w0, bf2f((unsigned short)v0), a0); a1 = fmaf(w0, bf2f((unsigned short)(v0 >> 16)), a1);
        a0 = fmaf(w1, bf2f((unsigned short)v1), a0); a1 = fmaf(w1, bf2f((unsigned short)(v1 >> 16)), a1);
        a0 = fmaf(w2, bf2f((unsigned short)v2), a0); a1 = fmaf(w2, bf2f((unsigned short)(v2 >> 16)), a1);
        a0 = fmaf(w3, bf2f((unsigned short)v3), a0); a1 = fmaf(w3, bf2f((unsigned short)(v3 >> 16)), a1);
    }
    for (; k < end; k++) {
        int i0 = csr_src[k];
        float w0 = csr_w[k];
        unsigned int v0 = sb[(size_t)i0 * 64];
        a0 = fmaf(w0, bf2f((unsigned short)v0), a0); a1 = fmaf(w0, bf2f((unsigned short)(v0 >> 16)), a1);
    }
    int c = slice * 32 + l * 2;  // h col 256+c
    float r0 = fmaxf(a0 + b1[256 + c], 0.f);
    float r1 = fmaxf(a1 + b1[256 + c + 1], 0.f);
    unsigned int o = (unsigned int)f2bf(r0) | ((unsigned int)f2bf(r1) << 16);
    ((unsigned int*)(Hb + (size_t)i * L1W + 256))[slice * 16 + l] = o;
}

// ---------------- fused width-80 bf16 prop (layer 2) ------------------------

__global__ __launch_bounds__(256) void prop80b_k(const unsigned short* __restrict__ Ub,
                                                 unsigned short* __restrict__ T2a,
                                                 unsigned short* __restrict__ T2b,
                                                 const int* __restrict__ rowptr,
                                                 const int* __restrict__ csr_src,
                                                 const float* __restrict__ csr_w,
                                                 const float* __restrict__ dinv, int n) {
    int wave = threadIdx.x >> 6, lane = threadIdx.x & 63;
    int i = blockIdx.x * 4 + wave;
    if (i >= n) return;
    int beg = rowptr[i], end = rowptr[i + 1];
    float di = dinv[i];
    bool act = lane < 40;
    const unsigned int* sbase = (const unsigned int*)(Ub + 40) + lane;
    float a0 = 0.f, a1 = 0.f;
    if (act) {
        unsigned int sv = sbase[(size_t)i * 64];
        float w = di * di;
        a0 = w * bf2f((unsigned short)sv); a1 = w * bf2f((unsigned short)(sv >> 16));
    }
    int k = beg;
    for (; k + 1 < end; k += 2) {
        int i0 = csr_src[k], i1 = csr_src[k + 1];
        float w0 = csr_w[k], w1 = csr_w[k + 1];
        if (act) {
            unsigned int v0 = sbase[(size_t)i0 * 64];
            unsigned int v1 = sbase[(size_t)i1 * 64];
            a0 = fmaf(w0, bf2f((unsigned short)v0), a0); a1 = fmaf(w0, bf2f((unsigned short)(v0 >> 16)), a1);
            a0 = fmaf(w1, bf2f((unsigned short)v1), a0); a1 = fmaf(w1, bf2f((unsigned short)(v1 >> 16)), a1);
        }
    }
    if (k < end) {
        int i0 = csr_src[k];
        float w0 = csr_w[k];
        if (act) {
            unsigned int v0 = sbase[(size_t)i0 * 64];
            a0 = fmaf(w0, bf2f((unsigned short)v0), a0); a1 = fmaf(w0, bf2f((unsigned short)(v0 >> 16)), a1);
        }
    }
    if (act) {
        unsigned int o = (unsigned int)f2bf(a0) | ((unsigned int)f2bf(a1) << 16);
        if (lane < 20) *((unsigned int*)T2a + (size_t)i * 20 + lane) = o;
        else *((unsigned int*)T2b + (size_t)i * 20 + (lane - 20)) = o;
    }
}

// ---------------- width-40 bf16 prop (2nd hop): Ub[:,80:120] = P(T2b) -------

__global__ __launch_bounds__(256) void prop40b_k(const unsigned short* __restrict__ T2b,
                                                 unsigned short* __restrict__ Ub,
                                                 const int* __restrict__ rowptr,
                                                 const int* __restrict__ csr_src,
                                                 const float* __restrict__ csr_w,
                                                 const float* __restrict__ dinv, int n) {
    int wave = threadIdx.x >> 6, lane = threadIdx.x & 63;
    int i = blockIdx.x * 4 + wave;
    if (i >= n) return;
    int beg = rowptr[i], end = rowptr[i + 1];
    float di = dinv[i];
    bool act = lane < 20;
    const unsigned int* sbase = (const unsigned int*)T2b + lane;
    float a0 = 0.f, a1 = 0.f;
    if (act) {
        unsigned int sv = sbase[(size_t)i * 20];
        float w = di * di;
        a0 = w * bf2f((unsigned short)sv); a1 = w * bf2f((unsigned short)(sv >> 16));
    }
    int k = beg;
    for (; k + 1 < end; k += 2) {
        int i0 = csr_src[k], i1 = csr_src[k + 1];
        float w0 = csr_w[k], w1 = csr_w[k + 1];
        if (act) {
            unsigned int v0 = sbase[(size_t)i0 * 20];
            unsigned int v1 = sbase[(size_t)i1 * 20];
            a0 = fmaf(w0, bf2f((unsigned short)v0), a0); a1 = fmaf(w0, bf2f((unsigned short)(v0 >> 16)), a1);
            a0 = fmaf(w1, bf2f((unsigned short)v1), a0); a1 = fmaf(w1, bf2f((unsigned short)(v1 >> 16)), a1);
        }
    }
    if (k < end) {
        int i0 = csr_src[k];
        float w0 = csr_w[k];
        if (act) {
            unsigned int v0 = sbase[(size_t)i0 * 20];
            a0 = fmaf(w0, bf2f((unsigned short)v0), a0); a1 = fmaf(w0, bf2f((unsigned short)(v0 >> 16)), a1);
        }
    }
    if (act) {
        unsigned int o = (unsigned int)f2bf(a0) | ((unsigned int)f2bf(a1) << 16);
        *((unsigned int*)Ub + (size_t)i * 64 + 40 + lane) = o;
    }
}

// ---------------- log_softmax epilogue (bf16 logits) ------------------------

__global__ __launch_bounds__(256) void lsm_k(const unsigned short* __restrict__ Ub,
                                             const unsigned short* __restrict__ T2a,
                                             const float* __restrict__ b2,
                                             float* __restrict__ out, int n) {
    int wave = threadIdx.x >> 6;
    int lane = threadIdx.x & 63;
    int i = blockIdx.x * 4 + wave;
    if (i >= n) return;
    float v0, v1;
    {
        int j = lane;  // 0..63
        float v = (j >= 40) ? bf2f(T2a[(size_t)i * 40 + (j - 40)]) : bf2f(Ub[(size_t)i * L2WP + j]);
        v0 = v + b2[j];
    }
    if (lane + 64 < 120) {
        int j = lane + 64;  // 64..119
        float v = (j < 80) ? bf2f(T2a[(size_t)i * 40 + (j - 40)]) : bf2f(Ub[(size_t)i * L2WP + j]);
        v1 = v + b2[j];
    } else {
        v1 = -INFINITY;
    }
    float m = fmaxf(v0, v1);
    for (int off = 32; off; off >>= 1) m = fmaxf(m, __shfl_xor(m, off, 64));
    float s = expf(v0 - m) + ((lane + 64 < 120) ? expf(v1 - m) : 0.f);
    for (int off = 32; off; off >>= 1) s += __shfl_xor(s, off, 64);
    float ls = logf(s) + m;
    out[(size_t)i * 120 + lane] = v0 - ls;
    if (lane + 64 < 120) out[(size_t)i * 120 + lane + 64] = v1 - ls;
}

// ---------------- launch ----------------

static inline size_t align256(size_t x) { return (x + 255) & ~(size_t)255; }

extern "C" void kernel_launch(void* const* d_in, const int* in_sizes, int n_in,
                              void* d_out, int out_size, void* d_ws, size_t ws_size,
                              hipStream_t stream) {
    const float* x = (const float*)d_in[0];
    const int* ei = (const int*)d_in[1];
    const float* W1_0 = (const float*)d_in[2];
    const float* W1_1 = (const float*)d_in[3];
    const float* W1_2 = (const float*)d_in[4];
    const float* b1 = (const float*)d_in[5];
    const float* W2_0 = (const float*)d_in[6];
    const float* W2_1 = (const float*)d_in[7];
    const float* W2_2 = (const float*)d_in[8];
    const float* b2 = (const float*)d_in[9];
    float* out = (float*)d_out;

    const int n = N_NODES;
    const int E = in_sizes[1] / 2;
    const int nb = (n + 255) / 256;
    const int nb16 = (n + 15) / 16;

    char* p = (char*)d_ws;
    size_t off = 0;
    auto alloc = [&](size_t bytes) {
        void* r = p + off;
        off = align256(off + bytes);
        return r;
    };
    int* flag = (int*)alloc(4);
    int* srcN = (int*)alloc((size_t)E * 4);
    int* dstN = (int*)alloc((size_t)E * 4);
    int* cnt = (int*)alloc((size_t)n * 4);
    int* rowptr = (int*)alloc((size_t)(n + 1) * 4);
    int* fill = (int*)alloc((size_t)n * 4);
    int* bsum = (int*)alloc((size_t)nb * 4);
    float* dinv = (float*)alloc((size_t)n * 4);
    int* csr_src = (int*)alloc((size_t)E * 4);
    float* csr_w = (float*)alloc((size_t)E * 4);
    unsigned short* Bp1 = (unsigned short*)alloc((size_t)(F_IN / 32) * L1W * 32 * 2);
    unsigned short* Bp2 = (unsigned short*)alloc((size_t)(L1W / 32) * L2WP * 32 * 2);
    unsigned short* Hb = (unsigned short*)alloc((size_t)n * L1W * 2);
    unsigned short* Y2b = (unsigned short*)alloc((size_t)n * 256 * 2);
    unsigned short* Tb = (unsigned short*)alloc((size_t)n * 128 * 2);
    unsigned short* Ub = (unsigned short*)alloc((size_t)n * L2WP * 2);
    unsigned short* T2a = (unsigned short*)alloc((size_t)n * C_OUT * 2);
    unsigned short* T2b = (unsigned short*)alloc((size_t)n * C_OUT * 2);
    (void)ws_size;

    // 0. edge dtype normalize
    detect_k<<<1, 256, 0, stream>>>(ei, flag);
    conv_k<<<(E + 255) / 256, 256, 0, stream>>>(ei, flag, srcN, dstN, E);

    // 1. CSR build
    hipMemsetAsync(cnt, 0, (size_t)n * 4, stream);
    hist_k<<<(E + 255) / 256, 256, 0, stream>>>(dstN, cnt, E);
    dinv_k<<<(n + 255) / 256, 256, 0, stream>>>(cnt, dinv, n);
    scan1_k<<<nb, 256, 0, stream>>>(cnt, bsum, n);
    scan2_k<<<1, 256, 0, stream>>>(bsum, rowptr + n, nb);
    scan3_k<<<nb, 256, 0, stream>>>(cnt, bsum, rowptr, fill, n);
    scatter_k<<<(E + 255) / 256, 256, 0, stream>>>(srcN, dstN, fill, csr_src, csr_w, dinv, E);

    // 2. weight packing
    pack1b_k<<<((F_IN / 32) * L1W * 32 + 255) / 256, 256, 0, stream>>>(W1_0, W1_1, W1_2, Bp1);
    pack2b_k<<<((L1W / 32) * L2WP * 32 + 255) / 256, 256, 0, stream>>>(W2_0, W2_1, W2_2, Bp2);

    // 3. layer 1 GEMM (LDS-staged B, fused cvt + bias/relu split store)
    mgemm1_k<<<(n + 63) / 64, 256, 0, stream>>>(x, Bp1, b1, Hb, Y2b, n);
    // XCD-sliced props: Hb[:,128:256] = relu(P(y1)+b1); Tb = P(y2)
    prop256s_k<<<8 * nb16, 256, 0, stream>>>(Y2b, Hb, Tb, rowptr, csr_src, csr_w, dinv, b1, n);
    // Hb[:,256:384] = relu(P(Tb)+b1)
    prop128s_k<<<4 * nb16, 256, 0, stream>>>(Tb, Hb, rowptr, csr_src, csr_w, dinv, b1, n);

    // 4. layer 2 GEMM -> bf16 Ub (LDS-staged B)
    mgemm2_k<<<(n + 63) / 64, 256, 0, stream>>>(Hb, Bp2, Ub, n);
    // fused: T2a = P(u1), T2b = P(u2)
    prop80b_k<<<(n + 3) / 4, 256, 0, stream>>>(Ub, T2a, T2b, rowptr, csr_src, csr_w, dinv, n);
    // second hop: Ub[:,80:120] = P(T2b)
    prop40b_k<<<(n + 3) / 4, 256, 0, stream>>>(T2b, Ub, rowptr, csr_src, csr_w, dinv, n);

    // 5. log_softmax epilogue
    lsm_k<<<(n + 3) / 4, 256, 0, stream>>>(Ub, T2a, b2, out, n);
}

// Round 9
// 445.005 us; speedup vs baseline: 1.1926x; 1.1728x over previous
//
#include <hip/hip_runtime.h>
#include <hip/hip_bf16.h>
#include <math.h>

#define N_NODES 50000
#define F_IN 256
#define H1 128
#define C_OUT 40
#define L1W 384   // 3*H1
#define L2W 120   // 3*C_OUT
#define L2WP 128  // padded

typedef __attribute__((ext_vector_type(8))) short short8;
typedef __attribute__((ext_vector_type(4))) float f32x4;
typedef __attribute__((ext_vector_type(4))) unsigned short us4;

__device__ inline unsigned short f2bf(float f) {
    union { float f; unsigned int u; } x;
    x.f = f;
    unsigned int u = x.u;
    return (unsigned short)((u + 0x7FFF + ((u >> 16) & 1)) >> 16);
}
__device__ inline float bf2f(unsigned short u) {
    union { unsigned int u; float f; } x;
    x.u = (unsigned int)u << 16;
    return x.f;
}

// ---------------- edge-index dtype detection + normalization ----------------

__global__ void detect_k(const int* __restrict__ ei, int* __restrict__ flag) {
    __shared__ int any;
    if (threadIdx.x == 0) any = 0;
    __syncthreads();
    int v = 0;
    for (int r = 0; r < 4; r++) {
        int e = threadIdx.x + r * 256;
        v |= ei[e * 2 + 1];
    }
    if (v != 0) atomicOr(&any, 1);
    __syncthreads();
    if (threadIdx.x == 0) *flag = any;  // 1 => int32 layout, 0 => int64
}

__global__ void conv_k(const int* __restrict__ ei, const int* __restrict__ flag,
                       int* __restrict__ srcN, int* __restrict__ dstN, int E) {
    int e = blockIdx.x * 256 + threadIdx.x;
    if (e >= E) return;
    if (*flag) {
        srcN[e] = ei[e];
        dstN[e] = ei[E + e];
    } else {
        const long long* e64 = (const long long*)ei;
        srcN[e] = (int)e64[e];
        dstN[e] = (int)e64[E + e];
    }
}

// ---------------- CSR build ----------------

__global__ void hist_k(const int* __restrict__ dst, int* __restrict__ cnt, int E) {
    int e = blockIdx.x * 256 + threadIdx.x;
    if (e < E) atomicAdd(&cnt[dst[e]], 1);
}

__global__ void dinv_k(const int* __restrict__ cnt, float* __restrict__ dinv, int n) {
    int i = blockIdx.x * 256 + threadIdx.x;
    if (i < n) dinv[i] = rsqrtf((float)cnt[i] + 1.0f);
}

__global__ __launch_bounds__(256) void scan1_k(const int* __restrict__ cnt,
                                               int* __restrict__ bsum, int n) {
    int t = threadIdx.x;
    int i = blockIdx.x * 256 + t;
    int v = (i < n) ? cnt[i] : 0;
    for (int off = 32; off; off >>= 1) v += __shfl_down(v, off, 64);
    __shared__ int ws[4];
    if ((t & 63) == 0) ws[t >> 6] = v;
    __syncthreads();
    if (t == 0) bsum[blockIdx.x] = ws[0] + ws[1] + ws[2] + ws[3];
}

__global__ __launch_bounds__(256) void scan2_k(int* __restrict__ bsum,
                                               int* __restrict__ btot, int nb) {
    __shared__ int s[256];
    int t = threadIdx.x;
    int v = (t < nb) ? bsum[t] : 0;
    s[t] = v;
    __syncthreads();
    for (int off = 1; off < 256; off <<= 1) {
        int u = (t >= off) ? s[t - off] : 0;
        __syncthreads();
        s[t] += u;
        __syncthreads();
    }
    if (t < nb) bsum[t] = s[t] - v;  // exclusive
    if (t == nb - 1) *btot = s[t];   // rowptr[n]
}

__global__ __launch_bounds__(256) void scan3_k(const int* __restrict__ cnt,
                                               const int* __restrict__ bsum,
                                               int* __restrict__ rowptr,
                                               int* __restrict__ fill, int n) {
    __shared__ int s[256];
    int t = threadIdx.x;
    int i = blockIdx.x * 256 + t;
    int v = (i < n) ? cnt[i] : 0;
    s[t] = v;
    __syncthreads();
    for (int off = 1; off < 256; off <<= 1) {
        int u = (t >= off) ? s[t - off] : 0;
        __syncthreads();
        s[t] += u;
        __syncthreads();
    }
    if (i < n) {
        int excl = s[t] - v + bsum[blockIdx.x];
        rowptr[i] = excl;
        fill[i] = excl;
    }
}

__global__ void scatter_k(const int* __restrict__ srcI, const int* __restrict__ dstI,
                          int* __restrict__ fill, int* __restrict__ csr_src,
                          float* __restrict__ csr_w, const float* __restrict__ dinv, int E) {
    int e = blockIdx.x * 256 + threadIdx.x;
    if (e >= E) return;
    int s = srcI[e], d = dstI[e];
    int pos = atomicAdd(&fill[d], 1);
    csr_src[pos] = s;
    csr_w[pos] = dinv[s] * dinv[d];
}

// ---------------- weight packing (bf16, B-fragment layout) ------------------
// Bp layout: [K/32][Mp][32]; frag addr = col*32 + kq*8.

__global__ void pack1b_k(const float* __restrict__ w0, const float* __restrict__ w1,
                         const float* __restrict__ w2, unsigned short* __restrict__ Bp) {
    int idx = blockIdx.x * 256 + threadIdx.x;
    if (idx >= (F_IN / 32) * L1W * 32) return;
    int kk = idx & 31;
    int nn = (idx >> 5) % L1W;
    int kt = idx / (L1W * 32);
    int k = kt * 32 + kk;
    int p = nn >> 7, c = nn & 127;
    const float* w = (p == 0) ? w0 : (p == 1) ? w1 : w2;
    Bp[idx] = f2bf(w[k * H1 + c]);
}

__global__ void pack2b_k(const float* __restrict__ w0, const float* __restrict__ w1,
                         const float* __restrict__ w2, unsigned short* __restrict__ Bp) {
    int idx = blockIdx.x * 256 + threadIdx.x;
    if (idx >= (L1W / 32) * L2WP * 32) return;
    int kk = idx & 31;
    int nn = (idx >> 5) & (L2WP - 1);
    int kt = idx >> 12;  // 128*32 = 4096
    int k = kt * 32 + kk;
    unsigned short v = 0;
    if (nn < L2W) {
        int p = nn / 40, c = nn % 40;
        const float* w = (p == 0) ? w0 : (p == 1) ? w1 : w2;
        v = f2bf(w[k * C_OUT + c]);
    }
    Bp[idx] = v;
}

// ---------------- layer-1 GEMM: LDS-staged B, fused cvt + bias/relu ---------

__global__ __launch_bounds__(256, 3) void mgemm1_k(const float* __restrict__ A,
                                                   const unsigned short* __restrict__ Bp,
                                                   const float* __restrict__ b1,
                                                   unsigned short* __restrict__ Hb,
                                                   unsigned short* __restrict__ Y2b, int N) {
    __shared__ unsigned short Bs[2][L1W * 32];  // 2 x 24576 B
    int tid = threadIdx.x;
    int wave = tid >> 6, lane = tid & 63;
    int m = lane & 15, kq = lane >> 4;
    int row0 = blockIdx.x * 64 + wave * 16;
    int arow = row0 + m;
    if (arow >= N) arow = N - 1;  // clamped duplicate; stores guarded
    const float* Ap = A + (size_t)arow * F_IN + kq * 8;

    f32x4 acc[24];
#pragma unroll
    for (int s = 0; s < 24; s++) acc[s] = (f32x4){0.f, 0.f, 0.f, 0.f};

    short8 breg[6];
    float4 af0, af1;
#pragma unroll
    for (int c = 0; c < 6; c++) {
        int t = tid + c * 256;
        breg[c] = *(const short8*)(Bp + (size_t)t * 8);
    }
    af0 = *(const float4*)(Ap);
    af1 = *(const float4*)(Ap + 4);
#pragma unroll
    for (int c = 0; c < 6; c++) {
        int t = tid + c * 256;
        int col = t >> 2, pp = t & 3;
        *(short8*)(&Bs[0][col * 32 + ((pp ^ ((col >> 1) & 3)) << 3)]) = breg[c];
    }
    __syncthreads();

    for (int kt = 0; kt < F_IN / 32; kt++) {
        short8 a;
        a[0] = (short)f2bf(af0.x); a[1] = (short)f2bf(af0.y);
        a[2] = (short)f2bf(af0.z); a[3] = (short)f2bf(af0.w);
        a[4] = (short)f2bf(af1.x); a[5] = (short)f2bf(af1.y);
        a[6] = (short)f2bf(af1.z); a[7] = (short)f2bf(af1.w);
        if (kt < F_IN / 32 - 1) {
            const unsigned short* Bn = Bp + (size_t)(kt + 1) * L1W * 32;
#pragma unroll
            for (int c = 0; c < 6; c++) {
                int t = tid + c * 256;
                breg[c] = *(const short8*)(Bn + (size_t)t * 8);
            }
            af0 = *(const float4*)(Ap + (kt + 1) * 32);
            af1 = *(const float4*)(Ap + (kt + 1) * 32 + 4);
        }
        const unsigned short* Bbuf = Bs[kt & 1];
#pragma unroll
        for (int s = 0; s < 24; s++) {
            int col = s * 16 + m;
            short8 b = *(const short8*)(&Bbuf[col * 32 + ((kq ^ ((col >> 1) & 3)) << 3)]);
            acc[s] = __builtin_amdgcn_mfma_f32_16x16x32_bf16(a, b, acc[s], 0, 0, 0);
        }
        if (kt < F_IN / 32 - 1) {
            int nb = (kt + 1) & 1;
#pragma unroll
            for (int c = 0; c < 6; c++) {
                int t = tid + c * 256;
                int col = t >> 2, pp = t & 3;
                *(short8*)(&Bs[nb][col * 32 + ((pp ^ ((col >> 1) & 3)) << 3)]) = breg[c];
            }
        }
        __syncthreads();
    }
    int crow = row0 + kq * 4;
#pragma unroll
    for (int s = 0; s < 24; s++) {
        int col = s * 16 + m;
        float bias = (col < 128) ? b1[col] : 0.f;
#pragma unroll
        for (int r = 0; r < 4; r++) {
            int row = crow + r;
            if (row < N) {
                float v = acc[s][r];
                if (col < 128) Hb[(size_t)row * L1W + col] = f2bf(fmaxf(v + bias, 0.f));
                else Y2b[(size_t)row * 256 + (col - 128)] = f2bf(v);
            }
        }
    }
}

// ---------------- layer-2 GEMM: LDS-staged B, bf16 out ----------------------

__global__ __launch_bounds__(256) void mgemm2_k(const unsigned short* __restrict__ A,
                                                const unsigned short* __restrict__ Bp,
                                                unsigned short* __restrict__ Ub, int N) {
    __shared__ unsigned short Bs[2][L2WP * 32];  // 2 x 8192 B
    int tid = threadIdx.x;
    int wave = tid >> 6, lane = tid & 63;
    int m = lane & 15, kq = lane >> 4;
    int row0 = blockIdx.x * 64 + wave * 16;
    int arow = row0 + m;
    if (arow >= N) arow = N - 1;
    const unsigned short* Ap = A + (size_t)arow * L1W + kq * 8;

    f32x4 acc[8];
#pragma unroll
    for (int s = 0; s < 8; s++) acc[s] = (f32x4){0.f, 0.f, 0.f, 0.f};

    short8 breg[2];
    short8 areg;
#pragma unroll
    for (int c = 0; c < 2; c++) {
        int t = tid + c * 256;
        breg[c] = *(const short8*)(Bp + (size_t)t * 8);
    }
    areg = *(const short8*)(Ap);
#pragma unroll
    for (int c = 0; c < 2; c++) {
        int t = tid + c * 256;
        int col = t >> 2, pp = t & 3;
        *(short8*)(&Bs[0][col * 32 + ((pp ^ ((col >> 1) & 3)) << 3)]) = breg[c];
    }
    __syncthreads();

    for (int kt = 0; kt < L1W / 32; kt++) {
        short8 a = areg;
        if (kt < L1W / 32 - 1) {
            const unsigned short* Bn = Bp + (size_t)(kt + 1) * L2WP * 32;
#pragma unroll
            for (int c = 0; c < 2; c++) {
                int t = tid + c * 256;
                breg[c] = *(const short8*)(Bn + (size_t)t * 8);
            }
            areg = *(const short8*)(Ap + (kt + 1) * 32);
        }
        const unsigned short* Bbuf = Bs[kt & 1];
#pragma unroll
        for (int s = 0; s < 8; s++) {
            int col = s * 16 + m;
            short8 b = *(const short8*)(&Bbuf[col * 32 + ((kq ^ ((col >> 1) & 3)) << 3)]);
            acc[s] = __builtin_amdgcn_mfma_f32_16x16x32_bf16(a, b, acc[s], 0, 0, 0);
        }
        if (kt < L1W / 32 - 1) {
            int nb = (kt + 1) & 1;
#pragma unroll
            for (int c = 0; c < 2; c++) {
                int t = tid + c * 256;
                int col = t >> 2, pp = t & 3;
                *(short8*)(&Bs[nb][col * 32 + ((pp ^ ((col >> 1) & 3)) << 3)]) = breg[c];
            }
        }
        __syncthreads();
    }
    int crow = row0 + kq * 4;
#pragma unroll
    for (int s = 0; s < 8; s++) {
        int col = s * 16 + m;
#pragma unroll
        for (int r = 0; r < 4; r++) {
            int row = crow + r;
            if (row < N) Ub[(size_t)row * L2WP + col] = f2bf(acc[s][r]);
        }
    }
}

// ---------------- fused width-256 bf16 prop over Y2b (de-sliced) ------------
// Wave-per-node, us4 (4 bf16)/lane = 512 B/row, 8-edge unroll.
// lanes 0..31: z1 -> relu(+b1) -> Hb[:,128:256]; lanes 32..63: t -> Tb.

__global__ __launch_bounds__(256) void prop256b_k(const unsigned short* __restrict__ Y2b,
                                                  unsigned short* __restrict__ Hb,
                                                  unsigned short* __restrict__ Tb,
                                                  const int* __restrict__ rowptr,
                                                  const int* __restrict__ csr_src,
                                                  const float* __restrict__ csr_w,
                                                  const float* __restrict__ dinv,
                                                  const float* __restrict__ b1, int n) {
    int wave = threadIdx.x >> 6, lane = threadIdx.x & 63;
    int i = blockIdx.x * 4 + wave;
    if (i >= n) return;
    int beg = rowptr[i], end = rowptr[i + 1];
    float di = dinv[i];
    const unsigned short* sbase = Y2b + (size_t)lane * 4;
    us4 sv = *(const us4*)(sbase + (size_t)i * 256);
    float w = di * di;
    float a0 = w * bf2f(sv.x), a1 = w * bf2f(sv.y), a2 = w * bf2f(sv.z), a3 = w * bf2f(sv.w);
    int k = beg;
    for (; k + 7 < end; k += 8) {
        int ii[8];
        float ww[8];
        us4 vv[8];
#pragma unroll
        for (int e = 0; e < 8; e++) { ii[e] = csr_src[k + e]; ww[e] = csr_w[k + e]; }
#pragma unroll
        for (int e = 0; e < 8; e++) vv[e] = *(const us4*)(sbase + (size_t)ii[e] * 256);
#pragma unroll
        for (int e = 0; e < 8; e++) {
            a0 = fmaf(ww[e], bf2f(vv[e].x), a0);
            a1 = fmaf(ww[e], bf2f(vv[e].y), a1);
            a2 = fmaf(ww[e], bf2f(vv[e].z), a2);
            a3 = fmaf(ww[e], bf2f(vv[e].w), a3);
        }
    }
    for (; k < end; k++) {
        int i0 = csr_src[k];
        float w0 = csr_w[k];
        us4 v0 = *(const us4*)(sbase + (size_t)i0 * 256);
        a0 = fmaf(w0, bf2f(v0.x), a0); a1 = fmaf(w0, bf2f(v0.y), a1);
        a2 = fmaf(w0, bf2f(v0.z), a2); a3 = fmaf(w0, bf2f(v0.w), a3);
    }
    int c = lane * 4;
    us4 o;
    if (c < 128) {  // z1 -> h cols 128..255, bias+relu
        const float4 b = *(const float4*)(b1 + 128 + c);
        o.x = f2bf(fmaxf(a0 + b.x, 0.f));
        o.y = f2bf(fmaxf(a1 + b.y, 0.f));
        o.z = f2bf(fmaxf(a2 + b.z, 0.f));
        o.w = f2bf(fmaxf(a3 + b.w, 0.f));
        *(us4*)(Hb + (size_t)i * L1W + 128 + c) = o;
    } else {        // t -> Tb
        o.x = f2bf(a0); o.y = f2bf(a1); o.z = f2bf(a2); o.w = f2bf(a3);
        *(us4*)(Tb + (size_t)i * 128 + (c - 128)) = o;
    }
}

// ---------------- width-128 bf16 prop: Hb[:,256:384] = relu(P(Tb)+b1) -------
// Wave-per-node, uint (2 bf16)/lane = 256 B/row, 8-edge unroll.

__global__ __launch_bounds__(256) void prop128b_k(const unsigned short* __restrict__ Tb,
                                                  unsigned short* __restrict__ Hb,
                                                  const int* __restrict__ rowptr,
                                                  const int* __restrict__ csr_src,
                                                  const float* __restrict__ csr_w,
                                                  const float* __restrict__ dinv,
                                                  const float* __restrict__ b1, int n) {
    int wave = threadIdx.x >> 6, lane = threadIdx.x & 63;
    int i = blockIdx.x * 4 + wave;
    if (i >= n) return;
    int beg = rowptr[i], end = rowptr[i + 1];
    float di = dinv[i];
    const unsigned int* sbase = (const unsigned int*)Tb + lane;
    unsigned int sv = sbase[(size_t)i * 64];
    float w = di * di;
    float a0 = w * bf2f((unsigned short)sv), a1 = w * bf2f((unsigned short)(sv >> 16));
    int k = beg;
    for (; k + 7 < end; k += 8) {
        int ii[8];
        float ww[8];
        unsigned int vv[8];
#pragma unroll
        for (int e = 0; e < 8; e++) { ii[e] = csr_src[k + e]; ww[e] = csr_w[k + e]; }
#pragma unroll
        for (int e = 0; e < 8; e++) vv[e] = sbase[(size_t)ii[e] * 64];
#pragma unroll
        for (int e = 0; e < 8; e++) {
            a0 = fmaf(ww[e], bf2f((unsigned short)vv[e]), a0);
            a1 = fmaf(ww[e], bf2f((unsigned short)(vv[e] >> 16)), a1);
        }
    }
    for (; k < end; k++) {
        int i0 = csr_src[k];
        float w0 = csr_w[k];
        unsigned int v0 = sbase[(size_t)i0 * 64];
        a0 = fmaf(w0, bf2f((unsigned short)v0), a0); a1 = fmaf(w0, bf2f((unsigned short)(v0 >> 16)), a1);
    }
    int c = lane * 2;  // h col 256+c
    float r0 = fmaxf(a0 + b1[256 + c], 0.f);
    float r1 = fmaxf(a1 + b1[256 + c + 1], 0.f);
    unsigned int o = (unsigned int)f2bf(r0) | ((unsigned int)f2bf(r1) << 16);
    *((unsigned int*)(Hb + (size_t)i * L1W + 256) + lane) = o;
}

// ---------------- fused width-80 bf16 prop (layer 2), 4-edge unroll ---------

__global__ __launch_bounds__(256) void prop80b_k(const unsigned short* __restrict__ Ub,
                                                 unsigned short* __restrict__ T2a,
                                                 unsigned short* __restrict__ T2b,
                                                 const int* __restrict__ rowptr,
                                                 const int* __restrict__ csr_src,
                                                 const float* __restrict__ csr_w,
                                                 const float* __restrict__ dinv, int n) {
    int wave = threadIdx.x >> 6, lane = threadIdx.x & 63;
    int i = blockIdx.x * 4 + wave;
    if (i >= n) return;
    int beg = rowptr[i], end = rowptr[i + 1];
    float di = dinv[i];
    bool act = lane < 40;
    const unsigned int* sbase = (const unsigned int*)(Ub + 40) + lane;
    float a0 = 0.f, a1 = 0.f;
    if (act) {
        unsigned int sv = sbase[(size_t)i * 64];
        float w = di * di;
        a0 = w * bf2f((unsigned short)sv); a1 = w * bf2f((unsigned short)(sv >> 16));
    }
    int k = beg;
    for (; k + 3 < end; k += 4) {
        int i0 = csr_src[k], i1 = csr_src[k + 1], i2 = csr_src[k + 2], i3 = csr_src[k + 3];
        float w0 = csr_w[k], w1 = csr_w[k + 1], w2 = csr_w[k + 2], w3 = csr_w[k + 3];
        if (act) {
            unsigned int v0 = sbase[(size_t)i0 * 64];
            unsigned int v1 = sbase[(size_t)i1 * 64];
            unsigned int v2 = sbase[(size_t)i2 * 64];
            unsigned int v3 = sbase[(size_t)i3 * 64];
            a0 = fmaf(w0, bf2f((unsigned short)v0), a0); a1 = fmaf(w0, bf2f((unsigned short)(v0 >> 16)), a1);
            a0 = fmaf(w1, bf2f((unsigned short)v1), a0); a1 = fmaf(w1, bf2f((unsigned short)(v1 >> 16)), a1);
            a0 = fmaf(w2, bf2f((unsigned short)v2), a0); a1 = fmaf(w2, bf2f((unsigned short)(v2 >> 16)), a1);
            a0 = fmaf(w3, bf2f((unsigned short)v3), a0); a1 = fmaf(w3, bf2f((unsigned short)(v3 >> 16)), a1);
        }
    }
    for (; k < end; k++) {
        int i0 = csr_src[k];
        float w0 = csr_w[k];
        if (act) {
            unsigned int v0 = sbase[(size_t)i0 * 64];
            a0 = fmaf(w0, bf2f((unsigned short)v0), a0); a1 = fmaf(w0, bf2f((unsigned short)(v0 >> 16)), a1);
        }
    }
    if (act) {
        unsigned int o = (unsigned int)f2bf(a0) | ((unsigned int)f2bf(a1) << 16);
        if (lane < 20) *((unsigned int*)T2a + (size_t)i * 20 + lane) = o;
        else *((unsigned int*)T2b + (size_t)i * 20 + (lane - 20)) = o;
    }
}

// ---------------- width-40 bf16 prop (2nd hop), 4-edge unroll ---------------

__global__ __launch_bounds__(256) void prop40b_k(const unsigned short* __restrict__ T2b,
                                                 unsigned short* __restrict__ Ub,
                                                 const int* __restrict__ rowptr,
                                                 const int* __restrict__ csr_src,
                                                 const float* __restrict__ csr_w,
                                                 const float* __restrict__ dinv, int n) {
    int wave = threadIdx.x >> 6, lane = threadIdx.x & 63;
    int i = blockIdx.x * 4 + wave;
    if (i >= n) return;
    int beg = rowptr[i], end = rowptr[i + 1];
    float di = dinv[i];
    bool act = lane < 20;
    const unsigned int* sbase = (const unsigned int*)T2b + lane;
    float a0 = 0.f, a1 = 0.f;
    if (act) {
        unsigned int sv = sbase[(size_t)i * 20];
        float w = di * di;
        a0 = w * bf2f((unsigned short)sv); a1 = w * bf2f((unsigned short)(sv >> 16));
    }
    int k = beg;
    for (; k + 3 < end; k += 4) {
        int i0 = csr_src[k], i1 = csr_src[k + 1], i2 = csr_src[k + 2], i3 = csr_src[k + 3];
        float w0 = csr_w[k], w1 = csr_w[k + 1], w2 = csr_w[k + 2], w3 = csr_w[k + 3];
        if (act) {
            unsigned int v0 = sbase[(size_t)i0 * 20];
            unsigned int v1 = sbase[(size_t)i1 * 20];
            unsigned int v2 = sbase[(size_t)i2 * 20];
            unsigned int v3 = sbase[(size_t)i3 * 20];
            a0 = fmaf(w0, bf2f((unsigned short)v0), a0); a1 = fmaf(w0, bf2f((unsigned short)(v0 >> 16)), a1);
            a0 = fmaf(w1, bf2f((unsigned short)v1), a0); a1 = fmaf(w1, bf2f((unsigned short)(v1 >> 16)), a1);
            a0 = fmaf(w2, bf2f((unsigned short)v2), a0); a1 = fmaf(w2, bf2f((unsigned short)(v2 >> 16)), a1);
            a0 = fmaf(w3, bf2f((unsigned short)v3), a0); a1 = fmaf(w3, bf2f((unsigned short)(v3 >> 16)), a1);
        }
    }
    for (; k < end; k++) {
        int i0 = csr_src[k];
        float w0 = csr_w[k];
        if (act) {
            unsigned int v0 = sbase[(size_t)i0 * 20];
            a0 = fmaf(w0, bf2f((unsigned short)v0), a0); a1 = fmaf(w0, bf2f((unsigned short)(v0 >> 16)), a1);
        }
    }
    if (act) {
        unsigned int o = (unsigned int)f2bf(a0) | ((unsigned int)f2bf(a1) << 16);
        *((unsigned int*)Ub + (size_t)i * 64 + 40 + lane) = o;
    }
}

// ---------------- log_softmax epilogue (bf16 logits) ------------------------

__global__ __launch_bounds__(256) void lsm_k(const unsigned short* __restrict__ Ub,
                                             const unsigned short* __restrict__ T2a,
                                             const float* __restrict__ b2,
                                             float* __restrict__ out, int n) {
    int wave = threadIdx.x >> 6;
    int lane = threadIdx.x & 63;
    int i = blockIdx.x * 4 + wave;
    if (i >= n) return;
    float v0, v1;
    {
        int j = lane;  // 0..63
        float v = (j >= 40) ? bf2f(T2a[(size_t)i * 40 + (j - 40)]) : bf2f(Ub[(size_t)i * L2WP + j]);
        v0 = v + b2[j];
    }
    if (lane + 64 < 120) {
        int j = lane + 64;  // 64..119
        float v = (j < 80) ? bf2f(T2a[(size_t)i * 40 + (j - 40)]) : bf2f(Ub[(size_t)i * L2WP + j]);
        v1 = v + b2[j];
    } else {
        v1 = -INFINITY;
    }
    float m = fmaxf(v0, v1);
    for (int off = 32; off; off >>= 1) m = fmaxf(m, __shfl_xor(m, off, 64));
    float s = expf(v0 - m) + ((lane + 64 < 120) ? expf(v1 - m) : 0.f);
    for (int off = 32; off; off >>= 1) s += __shfl_xor(s, off, 64);
    float ls = logf(s) + m;
    out[(size_t)i * 120 + lane] = v0 - ls;
    if (lane + 64 < 120) out[(size_t)i * 120 + lane + 64] = v1 - ls;
}

// ---------------- launch ----------------

static inline size_t align256(size_t x) { return (x + 255) & ~(size_t)255; }

extern "C" void kernel_launch(void* const* d_in, const int* in_sizes, int n_in,
                              void* d_out, int out_size, void* d_ws, size_t ws_size,
                              hipStream_t stream) {
    const float* x = (const float*)d_in[0];
    const int* ei = (const int*)d_in[1];
    const float* W1_0 = (const float*)d_in[2];
    const float* W1_1 = (const float*)d_in[3];
    const float* W1_2 = (const float*)d_in[4];
    const float* b1 = (const float*)d_in[5];
    const float* W2_0 = (const float*)d_in[6];
    const float* W2_1 = (const float*)d_in[7];
    const float* W2_2 = (const float*)d_in[8];
    const float* b2 = (const float*)d_in[9];
    float* out = (float*)d_out;

    const int n = N_NODES;
    const int E = in_sizes[1] / 2;
    const int nb = (n + 255) / 256;

    char* p = (char*)d_ws;
    size_t off = 0;
    auto alloc = [&](size_t bytes) {
        void* r = p + off;
        off = align256(off + bytes);
        return r;
    };
    int* flag = (int*)alloc(4);
    int* srcN = (int*)alloc((size_t)E * 4);
    int* dstN = (int*)alloc((size_t)E * 4);
    int* cnt = (int*)alloc((size_t)n * 4);
    int* rowptr = (int*)alloc((size_t)(n + 1) * 4);
    int* fill = (int*)alloc((size_t)n * 4);
    int* bsum = (int*)alloc((size_t)nb * 4);
    float* dinv = (float*)alloc((size_t)n * 4);
    int* csr_src = (int*)alloc((size_t)E * 4);
    float* csr_w = (float*)alloc((size_t)E * 4);
    unsigned short* Bp1 = (unsigned short*)alloc((size_t)(F_IN / 32) * L1W * 32 * 2);
    unsigned short* Bp2 = (unsigned short*)alloc((size_t)(L1W / 32) * L2WP * 32 * 2);
    unsigned short* Hb = (unsigned short*)alloc((size_t)n * L1W * 2);
    unsigned short* Y2b = (unsigned short*)alloc((size_t)n * 256 * 2);
    unsigned short* Tb = (unsigned short*)alloc((size_t)n * 128 * 2);
    unsigned short* Ub = (unsigned short*)alloc((size_t)n * L2WP * 2);
    unsigned short* T2a = (unsigned short*)alloc((size_t)n * C_OUT * 2);
    unsigned short* T2b = (unsigned short*)alloc((size_t)n * C_OUT * 2);
    (void)ws_size;

    // 0. edge dtype normalize
    detect_k<<<1, 256, 0, stream>>>(ei, flag);
    conv_k<<<(E + 255) / 256, 256, 0, stream>>>(ei, flag, srcN, dstN, E);

    // 1. CSR build
    hipMemsetAsync(cnt, 0, (size_t)n * 4, stream);
    hist_k<<<(E + 255) / 256, 256, 0, stream>>>(dstN, cnt, E);
    dinv_k<<<(n + 255) / 256, 256, 0, stream>>>(cnt, dinv, n);
    scan1_k<<<nb, 256, 0, stream>>>(cnt, bsum, n);
    scan2_k<<<1, 256, 0, stream>>>(bsum, rowptr + n, nb);
    scan3_k<<<nb, 256, 0, stream>>>(cnt, bsum, rowptr, fill, n);
    scatter_k<<<(E + 255) / 256, 256, 0, stream>>>(srcN, dstN, fill, csr_src, csr_w, dinv, E);

    // 2. weight packing
    pack1b_k<<<((F_IN / 32) * L1W * 32 + 255) / 256, 256, 0, stream>>>(W1_0, W1_1, W1_2, Bp1);
    pack2b_k<<<((L1W / 32) * L2WP * 32 + 255) / 256, 256, 0, stream>>>(W2_0, W2_1, W2_2, Bp2);

    // 3. layer 1 GEMM (LDS-staged B, fused cvt + bias/relu split store)
    mgemm1_k<<<(n + 63) / 64, 256, 0, stream>>>(x, Bp1, b1, Hb, Y2b, n);
    // fused prop: Hb[:,128:256] = relu(P(y1)+b1); Tb = P(y2)
    prop256b_k<<<(n + 3) / 4, 256, 0, stream>>>(Y2b, Hb, Tb, rowptr, csr_src, csr_w, dinv, b1, n);
    // Hb[:,256:384] = relu(P(Tb)+b1)
    prop128b_k<<<(n + 3) / 4, 256, 0, stream>>>(Tb, Hb, rowptr, csr_src, csr_w, dinv, b1, n);

    // 4. layer 2 GEMM -> bf16 Ub (LDS-staged B)
    mgemm2_k<<<(n + 63) / 64, 256, 0, stream>>>(Hb, Bp2, Ub, n);
    // fused: T2a = P(u1), T2b = P(u2)
    prop80b_k<<<(n + 3) / 4, 256, 0, stream>>>(Ub, T2a, T2b, rowptr, csr_src, csr_w, dinv, n);
    // second hop: Ub[:,80:120] = P(T2b)
    prop40b_k<<<(n + 3) / 4, 256, 0, stream>>>(T2b, Ub, rowptr, csr_src, csr_w, dinv, n);

    // 5. log_softmax epilogue
    lsm_k<<<(n + 3) / 4, 256, 0, stream>>>(Ub, T2a, b2, out, n);
}

// Round 10
// 429.446 us; speedup vs baseline: 1.2358x; 1.0362x over previous
//
#include <hip/hip_runtime.h>
#include <hip/hip_bf16.h>
#include <math.h>

#define N_NODES 50000
#define F_IN 256
#define H1 128
#define C_OUT 40
#define L1W 384   // 3*H1
#define L2W 120   // 3*C_OUT
#define L2WP 128  // padded

typedef __attribute__((ext_vector_type(8))) short short8;
typedef __attribute__((ext_vector_type(4))) float f32x4;
typedef __attribute__((ext_vector_type(4))) unsigned short us4;

__device__ inline unsigned short f2bf(float f) {
    union { float f; unsigned int u; } x;
    x.f = f;
    unsigned int u = x.u;
    return (unsigned short)((u + 0x7FFF + ((u >> 16) & 1)) >> 16);
}
__device__ inline float bf2f(unsigned short u) {
    union { unsigned int u; float f; } x;
    x.u = (unsigned int)u << 16;
    return x.f;
}

// ---------------- edge-index dtype detection --------------------------------

__global__ void detect_k(const int* __restrict__ ei, int* __restrict__ flag) {
    __shared__ int any;
    if (threadIdx.x == 0) any = 0;
    __syncthreads();
    int v = 0;
    for (int r = 0; r < 4; r++) {
        int e = threadIdx.x + r * 256;
        v |= ei[e * 2 + 1];
    }
    if (v != 0) atomicOr(&any, 1);
    __syncthreads();
    if (threadIdx.x == 0) *flag = any;  // 1 => int32 layout, 0 => int64
}

// ---------------- CSR build (conversion inlined) ----------------------------

__global__ void hist_k(const int* __restrict__ ei, const int* __restrict__ flag,
                       int* __restrict__ cnt, int E) {
    int e = blockIdx.x * 256 + threadIdx.x;
    if (e >= E) return;
    int d = (*flag) ? ei[E + e] : (int)((const long long*)ei)[E + e];
    atomicAdd(&cnt[d], 1);
}

__global__ void dinv_k(const int* __restrict__ cnt, float* __restrict__ dinv, int n) {
    int i = blockIdx.x * 256 + threadIdx.x;
    if (i < n) dinv[i] = rsqrtf((float)cnt[i] + 1.0f);
}

__global__ __launch_bounds__(256) void scan1_k(const int* __restrict__ cnt,
                                               int* __restrict__ bsum, int n) {
    int t = threadIdx.x;
    int i = blockIdx.x * 256 + t;
    int v = (i < n) ? cnt[i] : 0;
    for (int off = 32; off; off >>= 1) v += __shfl_down(v, off, 64);
    __shared__ int ws[4];
    if ((t & 63) == 0) ws[t >> 6] = v;
    __syncthreads();
    if (t == 0) bsum[blockIdx.x] = ws[0] + ws[1] + ws[2] + ws[3];
}

__global__ __launch_bounds__(256) void scan2_k(int* __restrict__ bsum,
                                               int* __restrict__ btot, int nb) {
    __shared__ int s[256];
    int t = threadIdx.x;
    int v = (t < nb) ? bsum[t] : 0;
    s[t] = v;
    __syncthreads();
    for (int off = 1; off < 256; off <<= 1) {
        int u = (t >= off) ? s[t - off] : 0;
        __syncthreads();
        s[t] += u;
        __syncthreads();
    }
    if (t < nb) bsum[t] = s[t] - v;  // exclusive
    if (t == nb - 1) *btot = s[t];   // rowptr[n]
}

__global__ __launch_bounds__(256) void scan3_k(const int* __restrict__ cnt,
                                               const int* __restrict__ bsum,
                                               int* __restrict__ rowptr,
                                               int* __restrict__ fill, int n) {
    __shared__ int s[256];
    int t = threadIdx.x;
    int i = blockIdx.x * 256 + t;
    int v = (i < n) ? cnt[i] : 0;
    s[t] = v;
    __syncthreads();
    for (int off = 1; off < 256; off <<= 1) {
        int u = (t >= off) ? s[t - off] : 0;
        __syncthreads();
        s[t] += u;
        __syncthreads();
    }
    if (i < n) {
        int excl = s[t] - v + bsum[blockIdx.x];
        rowptr[i] = excl;
        fill[i] = excl;
    }
}

// one 8B record per edge: {src, weight} -> single scattered store
__global__ void scatter_k(const int* __restrict__ ei, const int* __restrict__ flag,
                          int* __restrict__ fill, int2* __restrict__ csr,
                          const float* __restrict__ dinv, int E) {
    int e = blockIdx.x * 256 + threadIdx.x;
    if (e >= E) return;
    int s, d;
    if (*flag) {
        s = ei[e];
        d = ei[E + e];
    } else {
        const long long* e64 = (const long long*)ei;
        s = (int)e64[e];
        d = (int)e64[E + e];
    }
    int pos = atomicAdd(&fill[d], 1);
    int2 rec;
    rec.x = s;
    rec.y = __float_as_int(dinv[s] * dinv[d]);
    csr[pos] = rec;
}

// ---------------- weight packing (bf16, B-fragment layout) ------------------

__global__ void pack1b_k(const float* __restrict__ w0, const float* __restrict__ w1,
                         const float* __restrict__ w2, unsigned short* __restrict__ Bp) {
    int idx = blockIdx.x * 256 + threadIdx.x;
    if (idx >= (F_IN / 32) * L1W * 32) return;
    int kk = idx & 31;
    int nn = (idx >> 5) % L1W;
    int kt = idx / (L1W * 32);
    int k = kt * 32 + kk;
    int p = nn >> 7, c = nn & 127;
    const float* w = (p == 0) ? w0 : (p == 1) ? w1 : w2;
    Bp[idx] = f2bf(w[k * H1 + c]);
}

__global__ void pack2b_k(const float* __restrict__ w0, const float* __restrict__ w1,
                         const float* __restrict__ w2, unsigned short* __restrict__ Bp) {
    int idx = blockIdx.x * 256 + threadIdx.x;
    if (idx >= (L1W / 32) * L2WP * 32) return;
    int kk = idx & 31;
    int nn = (idx >> 5) & (L2WP - 1);
    int kt = idx >> 12;  // 128*32 = 4096
    int k = kt * 32 + kk;
    unsigned short v = 0;
    if (nn < L2W) {
        int p = nn / 40, c = nn % 40;
        const float* w = (p == 0) ? w0 : (p == 1) ? w1 : w2;
        v = f2bf(w[k * C_OUT + c]);
    }
    Bp[idx] = v;
}

// ---------------- layer-1 GEMM: LDS-staged B, fused cvt + bias/relu ---------

__global__ __launch_bounds__(256, 3) void mgemm1_k(const float* __restrict__ A,
                                                   const unsigned short* __restrict__ Bp,
                                                   const float* __restrict__ b1,
                                                   unsigned short* __restrict__ Hb,
                                                   unsigned short* __restrict__ Y2b, int N) {
    __shared__ unsigned short Bs[2][L1W * 32];  // 2 x 24576 B
    int tid = threadIdx.x;
    int wave = tid >> 6, lane = tid & 63;
    int m = lane & 15, kq = lane >> 4;
    int row0 = blockIdx.x * 64 + wave * 16;
    int arow = row0 + m;
    if (arow >= N) arow = N - 1;  // clamped duplicate; stores guarded
    const float* Ap = A + (size_t)arow * F_IN + kq * 8;

    f32x4 acc[24];
#pragma unroll
    for (int s = 0; s < 24; s++) acc[s] = (f32x4){0.f, 0.f, 0.f, 0.f};

    short8 breg[6];
    float4 af0, af1;
#pragma unroll
    for (int c = 0; c < 6; c++) {
        int t = tid + c * 256;
        breg[c] = *(const short8*)(Bp + (size_t)t * 8);
    }
    af0 = *(const float4*)(Ap);
    af1 = *(const float4*)(Ap + 4);
#pragma unroll
    for (int c = 0; c < 6; c++) {
        int t = tid + c * 256;
        int col = t >> 2, pp = t & 3;
        *(short8*)(&Bs[0][col * 32 + ((pp ^ ((col >> 1) & 3)) << 3)]) = breg[c];
    }
    __syncthreads();

    for (int kt = 0; kt < F_IN / 32; kt++) {
        short8 a;
        a[0] = (short)f2bf(af0.x); a[1] = (short)f2bf(af0.y);
        a[2] = (short)f2bf(af0.z); a[3] = (short)f2bf(af0.w);
        a[4] = (short)f2bf(af1.x); a[5] = (short)f2bf(af1.y);
        a[6] = (short)f2bf(af1.z); a[7] = (short)f2bf(af1.w);
        if (kt < F_IN / 32 - 1) {
            const unsigned short* Bn = Bp + (size_t)(kt + 1) * L1W * 32;
#pragma unroll
            for (int c = 0; c < 6; c++) {
                int t = tid + c * 256;
                breg[c] = *(const short8*)(Bn + (size_t)t * 8);
            }
            af0 = *(const float4*)(Ap + (kt + 1) * 32);
            af1 = *(const float4*)(Ap + (kt + 1) * 32 + 4);
        }
        const unsigned short* Bbuf = Bs[kt & 1];
#pragma unroll
        for (int s = 0; s < 24; s++) {
            int col = s * 16 + m;
            short8 b = *(const short8*)(&Bbuf[col * 32 + ((kq ^ ((col >> 1) & 3)) << 3)]);
            acc[s] = __builtin_amdgcn_mfma_f32_16x16x32_bf16(a, b, acc[s], 0, 0, 0);
        }
        if (kt < F_IN / 32 - 1) {
            int nb = (kt + 1) & 1;
#pragma unroll
            for (int c = 0; c < 6; c++) {
                int t = tid + c * 256;
                int col = t >> 2, pp = t & 3;
                *(short8*)(&Bs[nb][col * 32 + ((pp ^ ((col >> 1) & 3)) << 3)]) = breg[c];
            }
        }
        __syncthreads();
    }
    int crow = row0 + kq * 4;
#pragma unroll
    for (int s = 0; s < 24; s++) {
        int col = s * 16 + m;
        float bias = (col < 128) ? b1[col] : 0.f;
#pragma unroll
        for (int r = 0; r < 4; r++) {
            int row = crow + r;
            if (row < N) {
                float v = acc[s][r];
                if (col < 128) Hb[(size_t)row * L1W + col] = f2bf(fmaxf(v + bias, 0.f));
                else Y2b[(size_t)row * 256 + (col - 128)] = f2bf(v);
            }
        }
    }
}

// ---------------- layer-2 GEMM: LDS-staged B, bf16 out ----------------------

__global__ __launch_bounds__(256) void mgemm2_k(const unsigned short* __restrict__ A,
                                                const unsigned short* __restrict__ Bp,
                                                unsigned short* __restrict__ Ub, int N) {
    __shared__ unsigned short Bs[2][L2WP * 32];  // 2 x 8192 B
    int tid = threadIdx.x;
    int wave = tid >> 6, lane = tid & 63;
    int m = lane & 15, kq = lane >> 4;
    int row0 = blockIdx.x * 64 + wave * 16;
    int arow = row0 + m;
    if (arow >= N) arow = N - 1;
    const unsigned short* Ap = A + (size_t)arow * L1W + kq * 8;

    f32x4 acc[8];
#pragma unroll
    for (int s = 0; s < 8; s++) acc[s] = (f32x4){0.f, 0.f, 0.f, 0.f};

    short8 breg[2];
    short8 areg;
#pragma unroll
    for (int c = 0; c < 2; c++) {
        int t = tid + c * 256;
        breg[c] = *(const short8*)(Bp + (size_t)t * 8);
    }
    areg = *(const short8*)(Ap);
#pragma unroll
    for (int c = 0; c < 2; c++) {
        int t = tid + c * 256;
        int col = t >> 2, pp = t & 3;
        *(short8*)(&Bs[0][col * 32 + ((pp ^ ((col >> 1) & 3)) << 3)]) = breg[c];
    }
    __syncthreads();

    for (int kt = 0; kt < L1W / 32; kt++) {
        short8 a = areg;
        if (kt < L1W / 32 - 1) {
            const unsigned short* Bn = Bp + (size_t)(kt + 1) * L2WP * 32;
#pragma unroll
            for (int c = 0; c < 2; c++) {
                int t = tid + c * 256;
                breg[c] = *(const short8*)(Bn + (size_t)t * 8);
            }
            areg = *(const short8*)(Ap + (kt + 1) * 32);
        }
        const unsigned short* Bbuf = Bs[kt & 1];
#pragma unroll
        for (int s = 0; s < 8; s++) {
            int col = s * 16 + m;
            short8 b = *(const short8*)(&Bbuf[col * 32 + ((kq ^ ((col >> 1) & 3)) << 3)]);
            acc[s] = __builtin_amdgcn_mfma_f32_16x16x32_bf16(a, b, acc[s], 0, 0, 0);
        }
        if (kt < L1W / 32 - 1) {
            int nb = (kt + 1) & 1;
#pragma unroll
            for (int c = 0; c < 2; c++) {
                int t = tid + c * 256;
                int col = t >> 2, pp = t & 3;
                *(short8*)(&Bs[nb][col * 32 + ((pp ^ ((col >> 1) & 3)) << 3)]) = breg[c];
            }
        }
        __syncthreads();
    }
    int crow = row0 + kq * 4;
#pragma unroll
    for (int s = 0; s < 8; s++) {
        int col = s * 16 + m;
#pragma unroll
        for (int r = 0; r < 4; r++) {
            int row = crow + r;
            if (row < N) Ub[(size_t)row * L2WP + col] = f2bf(acc[s][r]);
        }
    }
}

// ---------------- fused width-256 bf16 prop over Y2b ------------------------
// Wave-per-node, us4 (4 bf16)/lane = 512 B/row, 8-edge unroll, int2 edge recs.
// lanes 0..31: z1 -> relu(+b1) -> Hb[:,128:256]; lanes 32..63: t -> Tb.

__global__ __launch_bounds__(256) void prop256b_k(const unsigned short* __restrict__ Y2b,
                                                  unsigned short* __restrict__ Hb,
                                                  unsigned short* __restrict__ Tb,
                                                  const int* __restrict__ rowptr,
                                                  const int2* __restrict__ csr,
                                                  const float* __restrict__ dinv,
                                                  const float* __restrict__ b1, int n) {
    int wave = threadIdx.x >> 6, lane = threadIdx.x & 63;
    int i = blockIdx.x * 4 + wave;
    if (i >= n) return;
    int beg = rowptr[i], end = rowptr[i + 1];
    float di = dinv[i];
    const unsigned short* sbase = Y2b + (size_t)lane * 4;
    us4 sv = *(const us4*)(sbase + (size_t)i * 256);
    float w = di * di;
    float a0 = w * bf2f(sv.x), a1 = w * bf2f(sv.y), a2 = w * bf2f(sv.z), a3 = w * bf2f(sv.w);
    int k = beg;
    for (; k + 7 < end; k += 8) {
        int2 rr[8];
        us4 vv[8];
#pragma unroll
        for (int e = 0; e < 8; e++) rr[e] = csr[k + e];
#pragma unroll
        for (int e = 0; e < 8; e++) vv[e] = *(const us4*)(sbase + (size_t)rr[e].x * 256);
#pragma unroll
        for (int e = 0; e < 8; e++) {
            float we = __int_as_float(rr[e].y);
            a0 = fmaf(we, bf2f(vv[e].x), a0);
            a1 = fmaf(we, bf2f(vv[e].y), a1);
            a2 = fmaf(we, bf2f(vv[e].z), a2);
            a3 = fmaf(we, bf2f(vv[e].w), a3);
        }
    }
    for (; k < end; k++) {
        int2 r0 = csr[k];
        float w0 = __int_as_float(r0.y);
        us4 v0 = *(const us4*)(sbase + (size_t)r0.x * 256);
        a0 = fmaf(w0, bf2f(v0.x), a0); a1 = fmaf(w0, bf2f(v0.y), a1);
        a2 = fmaf(w0, bf2f(v0.z), a2); a3 = fmaf(w0, bf2f(v0.w), a3);
    }
    int c = lane * 4;
    us4 o;
    if (c < 128) {  // z1 -> h cols 128..255, bias+relu
        const float4 b = *(const float4*)(b1 + 128 + c);
        o.x = f2bf(fmaxf(a0 + b.x, 0.f));
        o.y = f2bf(fmaxf(a1 + b.y, 0.f));
        o.z = f2bf(fmaxf(a2 + b.z, 0.f));
        o.w = f2bf(fmaxf(a3 + b.w, 0.f));
        *(us4*)(Hb + (size_t)i * L1W + 128 + c) = o;
    } else {        // t -> Tb
        o.x = f2bf(a0); o.y = f2bf(a1); o.z = f2bf(a2); o.w = f2bf(a3);
        *(us4*)(Tb + (size_t)i * 128 + (c - 128)) = o;
    }
}

// ---------------- width-128 bf16 prop: Hb[:,256:384] = relu(P(Tb)+b1) -------

__global__ __launch_bounds__(256) void prop128b_k(const unsigned short* __restrict__ Tb,
                                                  unsigned short* __restrict__ Hb,
                                                  const int* __restrict__ rowptr,
                                                  const int2* __restrict__ csr,
                                                  const float* __restrict__ dinv,
                                                  const float* __restrict__ b1, int n) {
    int wave = threadIdx.x >> 6, lane = threadIdx.x & 63;
    int i = blockIdx.x * 4 + wave;
    if (i >= n) return;
    int beg = rowptr[i], end = rowptr[i + 1];
    float di = dinv[i];
    const unsigned int* sbase = (const unsigned int*)Tb + lane;
    unsigned int sv = sbase[(size_t)i * 64];
    float w = di * di;
    float a0 = w * bf2f((unsigned short)sv), a1 = w * bf2f((unsigned short)(sv >> 16));
    int k = beg;
    for (; k + 7 < end; k += 8) {
        int2 rr[8];
        unsigned int vv[8];
#pragma unroll
        for (int e = 0; e < 8; e++) rr[e] = csr[k + e];
#pragma unroll
        for (int e = 0; e < 8; e++) vv[e] = sbase[(size_t)rr[e].x * 64];
#pragma unroll
        for (int e = 0; e < 8; e++) {
            float we = __int_as_float(rr[e].y);
            a0 = fmaf(we, bf2f((unsigned short)vv[e]), a0);
            a1 = fmaf(we, bf2f((unsigned short)(vv[e] >> 16)), a1);
        }
    }
    for (; k < end; k++) {
        int2 r0 = csr[k];
        float w0 = __int_as_float(r0.y);
        unsigned int v0 = sbase[(size_t)r0.x * 64];
        a0 = fmaf(w0, bf2f((unsigned short)v0), a0); a1 = fmaf(w0, bf2f((unsigned short)(v0 >> 16)), a1);
    }
    int c = lane * 2;  // h col 256+c
    float r0 = fmaxf(a0 + b1[256 + c], 0.f);
    float r1 = fmaxf(a1 + b1[256 + c + 1], 0.f);
    unsigned int o = (unsigned int)f2bf(r0) | ((unsigned int)f2bf(r1) << 16);
    *((unsigned int*)(Hb + (size_t)i * L1W + 256) + lane) = o;
}

// ---------------- fused width-80 bf16 prop (layer 2), 4-edge unroll ---------

__global__ __launch_bounds__(256) void prop80b_k(const unsigned short* __restrict__ Ub,
                                                 unsigned short* __restrict__ T2a,
                                                 unsigned short* __restrict__ T2b,
                                                 const int* __restrict__ rowptr,
                                                 const int2* __restrict__ csr,
                                                 const float* __restrict__ dinv, int n) {
    int wave = threadIdx.x >> 6, lane = threadIdx.x & 63;
    int i = blockIdx.x * 4 + wave;
    if (i >= n) return;
    int beg = rowptr[i], end = rowptr[i + 1];
    float di = dinv[i];
    bool act = lane < 40;
    const unsigned int* sbase = (const unsigned int*)(Ub + 40) + lane;
    float a0 = 0.f, a1 = 0.f;
    if (act) {
        unsigned int sv = sbase[(size_t)i * 64];
        float w = di * di;
        a0 = w * bf2f((unsigned short)sv); a1 = w * bf2f((unsigned short)(sv >> 16));
    }
    int k = beg;
    for (; k + 3 < end; k += 4) {
        int2 r0 = csr[k], r1 = csr[k + 1], r2 = csr[k + 2], r3 = csr[k + 3];
        if (act) {
            unsigned int v0 = sbase[(size_t)r0.x * 64];
            unsigned int v1 = sbase[(size_t)r1.x * 64];
            unsigned int v2 = sbase[(size_t)r2.x * 64];
            unsigned int v3 = sbase[(size_t)r3.x * 64];
            float w0 = __int_as_float(r0.y), w1 = __int_as_float(r1.y);
            float w2 = __int_as_float(r2.y), w3 = __int_as_float(r3.y);
            a0 = fmaf(w0, bf2f((unsigned short)v0), a0); a1 = fmaf(w0, bf2f((unsigned short)(v0 >> 16)), a1);
            a0 = fmaf(w1, bf2f((unsigned short)v1), a0); a1 = fmaf(w1, bf2f((unsigned short)(v1 >> 16)), a1);
            a0 = fmaf(w2, bf2f((unsigned short)v2), a0); a1 = fmaf(w2, bf2f((unsigned short)(v2 >> 16)), a1);
            a0 = fmaf(w3, bf2f((unsigned short)v3), a0); a1 = fmaf(w3, bf2f((unsigned short)(v3 >> 16)), a1);
        }
    }
    for (; k < end; k++) {
        int2 r0 = csr[k];
        if (act) {
            float w0 = __int_as_float(r0.y);
            unsigned int v0 = sbase[(size_t)r0.x * 64];
            a0 = fmaf(w0, bf2f((unsigned short)v0), a0); a1 = fmaf(w0, bf2f((unsigned short)(v0 >> 16)), a1);
        }
    }
    if (act) {
        unsigned int o = (unsigned int)f2bf(a0) | ((unsigned int)f2bf(a1) << 16);
        if (lane < 20) *((unsigned int*)T2a + (size_t)i * 20 + lane) = o;
        else *((unsigned int*)T2b + (size_t)i * 20 + (lane - 20)) = o;
    }
}

// ---------------- fused second-hop prop + log_softmax -----------------------
// cols 80..119 = P(T2b) computed in lanes 0..19 (2 cols each), redistributed
// via variable-lane shuffle; then standard 120-col log_softmax.

__global__ __launch_bounds__(256) void lsm_prop_k(const unsigned short* __restrict__ Ub,
                                                  const unsigned short* __restrict__ T2a,
                                                  const unsigned short* __restrict__ T2b,
                                                  const int* __restrict__ rowptr,
                                                  const int2* __restrict__ csr,
                                                  const float* __restrict__ dinv,
                                                  const float* __restrict__ b2,
                                                  float* __restrict__ out, int n) {
    int wave = threadIdx.x >> 6;
    int lane = threadIdx.x & 63;
    int i = blockIdx.x * 4 + wave;
    if (i >= n) return;
    // --- second hop gather (lanes 0..19; 20 uints = 40 bf16 cols) ---
    int beg = rowptr[i], end = rowptr[i + 1];
    float di = dinv[i];
    bool act = lane < 20;
    const unsigned int* sbase = (const unsigned int*)T2b + lane;
    float a0 = 0.f, a1 = 0.f;
    if (act) {
        unsigned int sv = sbase[(size_t)i * 20];
        float w = di * di;
        a0 = w * bf2f((unsigned short)sv); a1 = w * bf2f((unsigned short)(sv >> 16));
    }
    int k = beg;
    for (; k + 3 < end; k += 4) {
        int2 r0 = csr[k], r1 = csr[k + 1], r2 = csr[k + 2], r3 = csr[k + 3];
        if (act) {
            unsigned int v0 = sbase[(size_t)r0.x * 20];
            unsigned int v1 = sbase[(size_t)r1.x * 20];
            unsigned int v2 = sbase[(size_t)r2.x * 20];
            unsigned int v3 = sbase[(size_t)r3.x * 20];
            float w0 = __int_as_float(r0.y), w1 = __int_as_float(r1.y);
            float w2 = __int_as_float(r2.y), w3 = __int_as_float(r3.y);
            a0 = fmaf(w0, bf2f((unsigned short)v0), a0); a1 = fmaf(w0, bf2f((unsigned short)(v0 >> 16)), a1);
            a0 = fmaf(w1, bf2f((unsigned short)v1), a0); a1 = fmaf(w1, bf2f((unsigned short)(v1 >> 16)), a1);
            a0 = fmaf(w2, bf2f((unsigned short)v2), a0); a1 = fmaf(w2, bf2f((unsigned short)(v2 >> 16)), a1);
            a0 = fmaf(w3, bf2f((unsigned short)v3), a0); a1 = fmaf(w3, bf2f((unsigned short)(v3 >> 16)), a1);
        }
    }
    for (; k < end; k++) {
        int2 r0 = csr[k];
        if (act) {
            float w0 = __int_as_float(r0.y);
            unsigned int v0 = sbase[(size_t)r0.x * 20];
            a0 = fmaf(w0, bf2f((unsigned short)v0), a0); a1 = fmaf(w0, bf2f((unsigned short)(v0 >> 16)), a1);
        }
    }
    // --- redistribute: lane holds col j1 = lane+64; for j1 in [80,120) value
    // lives in lane (j1-80)>>1, component (j1-80)&1 ---
    int j1 = lane + 64;
    int srcl = (j1 - 80) >> 1;
    float pa = __shfl(a0, srcl, 64);
    float pb = __shfl(a1, srcl, 64);
    float pv = ((j1 - 80) & 1) ? pb : pa;
    // --- assemble logits ---
    float v0, v1;
    {
        int j = lane;  // 0..63
        float v = (j >= 40) ? bf2f(T2a[(size_t)i * 40 + (j - 40)]) : bf2f(Ub[(size_t)i * L2WP + j]);
        v0 = v + b2[j];
    }
    if (j1 < 120) {
        float v = (j1 < 80) ? bf2f(T2a[(size_t)i * 40 + (j1 - 40)]) : pv;
        v1 = v + b2[j1];
    } else {
        v1 = -INFINITY;
    }
    float m = fmaxf(v0, v1);
    for (int off = 32; off; off >>= 1) m = fmaxf(m, __shfl_xor(m, off, 64));
    float s = expf(v0 - m) + ((j1 < 120) ? expf(v1 - m) : 0.f);
    for (int off = 32; off; off >>= 1) s += __shfl_xor(s, off, 64);
    float ls = logf(s) + m;
    out[(size_t)i * 120 + lane] = v0 - ls;
    if (j1 < 120) out[(size_t)i * 120 + j1] = v1 - ls;
}

// ---------------- launch ----------------

static inline size_t align256(size_t x) { return (x + 255) & ~(size_t)255; }

extern "C" void kernel_launch(void* const* d_in, const int* in_sizes, int n_in,
                              void* d_out, int out_size, void* d_ws, size_t ws_size,
                              hipStream_t stream) {
    const float* x = (const float*)d_in[0];
    const int* ei = (const int*)d_in[1];
    const float* W1_0 = (const float*)d_in[2];
    const float* W1_1 = (const float*)d_in[3];
    const float* W1_2 = (const float*)d_in[4];
    const float* b1 = (const float*)d_in[5];
    const float* W2_0 = (const float*)d_in[6];
    const float* W2_1 = (const float*)d_in[7];
    const float* W2_2 = (const float*)d_in[8];
    const float* b2 = (const float*)d_in[9];
    float* out = (float*)d_out;

    const int n = N_NODES;
    const int E = in_sizes[1] / 2;
    const int nb = (n + 255) / 256;

    char* p = (char*)d_ws;
    size_t off = 0;
    auto alloc = [&](size_t bytes) {
        void* r = p + off;
        off = align256(off + bytes);
        return r;
    };
    int* flag = (int*)alloc(4);
    int* cnt = (int*)alloc((size_t)n * 4);
    int* rowptr = (int*)alloc((size_t)(n + 1) * 4);
    int* fill = (int*)alloc((size_t)n * 4);
    int* bsum = (int*)alloc((size_t)nb * 4);
    float* dinv = (float*)alloc((size_t)n * 4);
    int2* csr = (int2*)alloc((size_t)E * 8);
    unsigned short* Bp1 = (unsigned short*)alloc((size_t)(F_IN / 32) * L1W * 32 * 2);
    unsigned short* Bp2 = (unsigned short*)alloc((size_t)(L1W / 32) * L2WP * 32 * 2);
    unsigned short* Hb = (unsigned short*)alloc((size_t)n * L1W * 2);
    unsigned short* Y2b = (unsigned short*)alloc((size_t)n * 256 * 2);
    unsigned short* Tb = (unsigned short*)alloc((size_t)n * 128 * 2);
    unsigned short* Ub = (unsigned short*)alloc((size_t)n * L2WP * 2);
    unsigned short* T2a = (unsigned short*)alloc((size_t)n * C_OUT * 2);
    unsigned short* T2b = (unsigned short*)alloc((size_t)n * C_OUT * 2);
    (void)ws_size;

    // 0. edge dtype detect
    detect_k<<<1, 256, 0, stream>>>(ei, flag);

    // 1. CSR build (conversion inlined into hist/scatter)
    hipMemsetAsync(cnt, 0, (size_t)n * 4, stream);
    hist_k<<<(E + 255) / 256, 256, 0, stream>>>(ei, flag, cnt, E);
    dinv_k<<<(n + 255) / 256, 256, 0, stream>>>(cnt, dinv, n);
    scan1_k<<<nb, 256, 0, stream>>>(cnt, bsum, n);
    scan2_k<<<1, 256, 0, stream>>>(bsum, rowptr + n, nb);
    scan3_k<<<nb, 256, 0, stream>>>(cnt, bsum, rowptr, fill, n);
    scatter_k<<<(E + 255) / 256, 256, 0, stream>>>(ei, flag, fill, csr, dinv, E);

    // 2. weight packing
    pack1b_k<<<((F_IN / 32) * L1W * 32 + 255) / 256, 256, 0, stream>>>(W1_0, W1_1, W1_2, Bp1);
    pack2b_k<<<((L1W / 32) * L2WP * 32 + 255) / 256, 256, 0, stream>>>(W2_0, W2_1, W2_2, Bp2);

    // 3. layer 1 GEMM (LDS-staged B, fused cvt + bias/relu split store)
    mgemm1_k<<<(n + 63) / 64, 256, 0, stream>>>(x, Bp1, b1, Hb, Y2b, n);
    // fused prop: Hb[:,128:256] = relu(P(y1)+b1); Tb = P(y2)
    prop256b_k<<<(n + 3) / 4, 256, 0, stream>>>(Y2b, Hb, Tb, rowptr, csr, dinv, b1, n);
    // Hb[:,256:384] = relu(P(Tb)+b1)
    prop128b_k<<<(n + 3) / 4, 256, 0, stream>>>(Tb, Hb, rowptr, csr, dinv, b1, n);

    // 4. layer 2 GEMM -> bf16 Ub (LDS-staged B)
    mgemm2_k<<<(n + 63) / 64, 256, 0, stream>>>(Hb, Bp2, Ub, n);
    // fused: T2a = P(u1), T2b = P(u2)
    prop80b_k<<<(n + 3) / 4, 256, 0, stream>>>(Ub, T2a, T2b, rowptr, csr, dinv, n);

    // 5. fused second hop + log_softmax
    lsm_prop_k<<<(n + 3) / 4, 256, 0, stream>>>(Ub, T2a, T2b, rowptr, csr, dinv, b2, out, n);
}

// Round 11
// 405.415 us; speedup vs baseline: 1.3090x; 1.0593x over previous
//
#include <hip/hip_runtime.h>
#include <hip/hip_bf16.h>
#include <math.h>

#define N_NODES 50000
#define F_IN 256
#define H1 128
#define C_OUT 40
#define L1W 384   // 3*H1
#define L2W 120   // 3*C_OUT
#define L2WP 128  // padded

typedef __attribute__((ext_vector_type(8))) short short8;
typedef __attribute__((ext_vector_type(4))) float f32x4;
typedef __attribute__((ext_vector_type(2))) float f32x2;
typedef __attribute__((ext_vector_type(4))) unsigned short us4;

__device__ inline unsigned short f2bf(float f) {
    union { float f; unsigned int u; } x;
    x.f = f;
    unsigned int u = x.u;
    return (unsigned short)((u + 0x7FFF + ((u >> 16) & 1)) >> 16);
}
__device__ inline float bf2f(unsigned short u) {
    union { unsigned int u; float f; } x;
    x.u = (unsigned int)u << 16;
    return x.f;
}
// pack 4 floats -> 4 fp8 (e4m3, HW cvt; self-consistent with decode below)
__device__ inline unsigned int pack_fp8x4(float a, float b, float c, float d) {
    int v = 0;
    v = __builtin_amdgcn_cvt_pk_fp8_f32(a, b, v, false);  // bytes 0,1
    v = __builtin_amdgcn_cvt_pk_fp8_f32(c, d, v, true);   // bytes 2,3
    return (unsigned int)v;
}

// ---------------- edge-index dtype detection --------------------------------

__global__ void detect_k(const int* __restrict__ ei, int* __restrict__ flag) {
    __shared__ int any;
    if (threadIdx.x == 0) any = 0;
    __syncthreads();
    int v = 0;
    for (int r = 0; r < 4; r++) {
        int e = threadIdx.x + r * 256;
        v |= ei[e * 2 + 1];
    }
    if (v != 0) atomicOr(&any, 1);
    __syncthreads();
    if (threadIdx.x == 0) *flag = any;  // 1 => int32 layout, 0 => int64
}

// ---------------- CSR build (conversion inlined) ----------------------------

__global__ void hist_k(const int* __restrict__ ei, const int* __restrict__ flag,
                       int* __restrict__ cnt, int E) {
    int e = blockIdx.x * 256 + threadIdx.x;
    if (e >= E) return;
    int d = (*flag) ? ei[E + e] : (int)((const long long*)ei)[E + e];
    atomicAdd(&cnt[d], 1);
}

__global__ void dinv_k(const int* __restrict__ cnt, float* __restrict__ dinv, int n) {
    int i = blockIdx.x * 256 + threadIdx.x;
    if (i < n) dinv[i] = rsqrtf((float)cnt[i] + 1.0f);
}

__global__ __launch_bounds__(256) void scan1_k(const int* __restrict__ cnt,
                                               int* __restrict__ bsum, int n) {
    int t = threadIdx.x;
    int i = blockIdx.x * 256 + t;
    int v = (i < n) ? cnt[i] : 0;
    for (int off = 32; off; off >>= 1) v += __shfl_down(v, off, 64);
    __shared__ int ws[4];
    if ((t & 63) == 0) ws[t >> 6] = v;
    __syncthreads();
    if (t == 0) bsum[blockIdx.x] = ws[0] + ws[1] + ws[2] + ws[3];
}

__global__ __launch_bounds__(256) void scan2_k(int* __restrict__ bsum,
                                               int* __restrict__ btot, int nb) {
    __shared__ int s[256];
    int t = threadIdx.x;
    int v = (t < nb) ? bsum[t] : 0;
    s[t] = v;
    __syncthreads();
    for (int off = 1; off < 256; off <<= 1) {
        int u = (t >= off) ? s[t - off] : 0;
        __syncthreads();
        s[t] += u;
        __syncthreads();
    }
    if (t < nb) bsum[t] = s[t] - v;  // exclusive
    if (t == nb - 1) *btot = s[t];   // rowptr[n]
}

__global__ __launch_bounds__(256) void scan3_k(const int* __restrict__ cnt,
                                               const int* __restrict__ bsum,
                                               int* __restrict__ rowptr,
                                               int* __restrict__ fill, int n) {
    __shared__ int s[256];
    int t = threadIdx.x;
    int i = blockIdx.x * 256 + t;
    int v = (i < n) ? cnt[i] : 0;
    s[t] = v;
    __syncthreads();
    for (int off = 1; off < 256; off <<= 1) {
        int u = (t >= off) ? s[t - off] : 0;
        __syncthreads();
        s[t] += u;
        __syncthreads();
    }
    if (i < n) {
        int excl = s[t] - v + bsum[blockIdx.x];
        rowptr[i] = excl;
        fill[i] = excl;
    }
}

// one 8B record per edge: {src, weight} -> single scattered store
__global__ void scatter_k(const int* __restrict__ ei, const int* __restrict__ flag,
                          int* __restrict__ fill, int2* __restrict__ csr,
                          const float* __restrict__ dinv, int E) {
    int e = blockIdx.x * 256 + threadIdx.x;
    if (e >= E) return;
    int s, d;
    if (*flag) {
        s = ei[e];
        d = ei[E + e];
    } else {
        const long long* e64 = (const long long*)ei;
        s = (int)e64[e];
        d = (int)e64[E + e];
    }
    int pos = atomicAdd(&fill[d], 1);
    int2 rec;
    rec.x = s;
    rec.y = __float_as_int(dinv[s] * dinv[d]);
    csr[pos] = rec;
}

// ---------------- weight packing (bf16, B-fragment layout) ------------------

__global__ void pack1b_k(const float* __restrict__ w0, const float* __restrict__ w1,
                         const float* __restrict__ w2, unsigned short* __restrict__ Bp) {
    int idx = blockIdx.x * 256 + threadIdx.x;
    if (idx >= (F_IN / 32) * L1W * 32) return;
    int kk = idx & 31;
    int nn = (idx >> 5) % L1W;
    int kt = idx / (L1W * 32);
    int k = kt * 32 + kk;
    int p = nn >> 7, c = nn & 127;
    const float* w = (p == 0) ? w0 : (p == 1) ? w1 : w2;
    Bp[idx] = f2bf(w[k * H1 + c]);
}

__global__ void pack2b_k(const float* __restrict__ w0, const float* __restrict__ w1,
                         const float* __restrict__ w2, unsigned short* __restrict__ Bp) {
    int idx = blockIdx.x * 256 + threadIdx.x;
    if (idx >= (L1W / 32) * L2WP * 32) return;
    int kk = idx & 31;
    int nn = (idx >> 5) & (L2WP - 1);
    int kt = idx >> 12;  // 128*32 = 4096
    int k = kt * 32 + kk;
    unsigned short v = 0;
    if (nn < L2W) {
        int p = nn / 40, c = nn % 40;
        const float* w = (p == 0) ? w0 : (p == 1) ? w1 : w2;
        v = f2bf(w[k * C_OUT + c]);
    }
    Bp[idx] = v;
}

// ---------------- layer-1 GEMM: LDS-staged B, fused cvt + bias/relu ---------
// cols 0:128 -> relu(+b1) bf16 -> Hb[:,0:128]
// cols 128:384 -> fp8 Y8 [n x 256 B], TRANSPOSED phys layout: phys = m*16 + (s-8)
// (so each lane stores one uint4 = 16 fp8 per row).

__global__ __launch_bounds__(256, 3) void mgemm1_k(const float* __restrict__ A,
                                                   const unsigned short* __restrict__ Bp,
                                                   const float* __restrict__ b1,
                                                   unsigned short* __restrict__ Hb,
                                                   unsigned char* __restrict__ Y8, int N) {
    __shared__ unsigned short Bs[2][L1W * 32];  // 2 x 24576 B
    int tid = threadIdx.x;
    int wave = tid >> 6, lane = tid & 63;
    int m = lane & 15, kq = lane >> 4;
    int row0 = blockIdx.x * 64 + wave * 16;
    int arow = row0 + m;
    if (arow >= N) arow = N - 1;  // clamped duplicate; stores guarded
    const float* Ap = A + (size_t)arow * F_IN + kq * 8;

    f32x4 acc[24];
#pragma unroll
    for (int s = 0; s < 24; s++) acc[s] = (f32x4){0.f, 0.f, 0.f, 0.f};

    short8 breg[6];
    float4 af0, af1;
#pragma unroll
    for (int c = 0; c < 6; c++) {
        int t = tid + c * 256;
        breg[c] = *(const short8*)(Bp + (size_t)t * 8);
    }
    af0 = *(const float4*)(Ap);
    af1 = *(const float4*)(Ap + 4);
#pragma unroll
    for (int c = 0; c < 6; c++) {
        int t = tid + c * 256;
        int col = t >> 2, pp = t & 3;
        *(short8*)(&Bs[0][col * 32 + ((pp ^ ((col >> 1) & 3)) << 3)]) = breg[c];
    }
    __syncthreads();

    for (int kt = 0; kt < F_IN / 32; kt++) {
        short8 a;
        a[0] = (short)f2bf(af0.x); a[1] = (short)f2bf(af0.y);
        a[2] = (short)f2bf(af0.z); a[3] = (short)f2bf(af0.w);
        a[4] = (short)f2bf(af1.x); a[5] = (short)f2bf(af1.y);
        a[6] = (short)f2bf(af1.z); a[7] = (short)f2bf(af1.w);
        if (kt < F_IN / 32 - 1) {
            const unsigned short* Bn = Bp + (size_t)(kt + 1) * L1W * 32;
#pragma unroll
            for (int c = 0; c < 6; c++) {
                int t = tid + c * 256;
                breg[c] = *(const short8*)(Bn + (size_t)t * 8);
            }
            af0 = *(const float4*)(Ap + (kt + 1) * 32);
            af1 = *(const float4*)(Ap + (kt + 1) * 32 + 4);
        }
        const unsigned short* Bbuf = Bs[kt & 1];
#pragma unroll
        for (int s = 0; s < 24; s++) {
            int col = s * 16 + m;
            short8 b = *(const short8*)(&Bbuf[col * 32 + ((kq ^ ((col >> 1) & 3)) << 3)]);
            acc[s] = __builtin_amdgcn_mfma_f32_16x16x32_bf16(a, b, acc[s], 0, 0, 0);
        }
        if (kt < F_IN / 32 - 1) {
            int nb = (kt + 1) & 1;
#pragma unroll
            for (int c = 0; c < 6; c++) {
                int t = tid + c * 256;
                int col = t >> 2, pp = t & 3;
                *(short8*)(&Bs[nb][col * 32 + ((pp ^ ((col >> 1) & 3)) << 3)]) = breg[c];
            }
        }
        __syncthreads();
    }
    int crow = row0 + kq * 4;
    // z1 half: cols 0..127 -> Hb bf16 relu
#pragma unroll
    for (int s = 0; s < 8; s++) {
        int col = s * 16 + m;
        float bias = b1[col];
#pragma unroll
        for (int r = 0; r < 4; r++) {
            int row = crow + r;
            if (row < N) Hb[(size_t)row * L1W + col] = f2bf(fmaxf(acc[s][r] + bias, 0.f));
        }
    }
    // y2 half: s in [8,24) -> fp8 transposed: phys byte = m*16 + (s-8)
#pragma unroll
    for (int r = 0; r < 4; r++) {
        int row = crow + r;
        if (row < N) {
            uint4 u;
            u.x = pack_fp8x4(acc[8][r], acc[9][r], acc[10][r], acc[11][r]);
            u.y = pack_fp8x4(acc[12][r], acc[13][r], acc[14][r], acc[15][r]);
            u.z = pack_fp8x4(acc[16][r], acc[17][r], acc[18][r], acc[19][r]);
            u.w = pack_fp8x4(acc[20][r], acc[21][r], acc[22][r], acc[23][r]);
            *(uint4*)(Y8 + (size_t)row * 256 + m * 16) = u;
        }
    }
}

// ---------------- layer-2 GEMM: LDS-staged B, bf16 out ----------------------

__global__ __launch_bounds__(256) void mgemm2_k(const unsigned short* __restrict__ A,
                                                const unsigned short* __restrict__ Bp,
                                                unsigned short* __restrict__ Ub, int N) {
    __shared__ unsigned short Bs[2][L2WP * 32];  // 2 x 8192 B
    int tid = threadIdx.x;
    int wave = tid >> 6, lane = tid & 63;
    int m = lane & 15, kq = lane >> 4;
    int row0 = blockIdx.x * 64 + wave * 16;
    int arow = row0 + m;
    if (arow >= N) arow = N - 1;
    const unsigned short* Ap = A + (size_t)arow * L1W + kq * 8;

    f32x4 acc[8];
#pragma unroll
    for (int s = 0; s < 8; s++) acc[s] = (f32x4){0.f, 0.f, 0.f, 0.f};

    short8 breg[2];
    short8 areg;
#pragma unroll
    for (int c = 0; c < 2; c++) {
        int t = tid + c * 256;
        breg[c] = *(const short8*)(Bp + (size_t)t * 8);
    }
    areg = *(const short8*)(Ap);
#pragma unroll
    for (int c = 0; c < 2; c++) {
        int t = tid + c * 256;
        int col = t >> 2, pp = t & 3;
        *(short8*)(&Bs[0][col * 32 + ((pp ^ ((col >> 1) & 3)) << 3)]) = breg[c];
    }
    __syncthreads();

    for (int kt = 0; kt < L1W / 32; kt++) {
        short8 a = areg;
        if (kt < L1W / 32 - 1) {
            const unsigned short* Bn = Bp + (size_t)(kt + 1) * L2WP * 32;
#pragma unroll
            for (int c = 0; c < 2; c++) {
                int t = tid + c * 256;
                breg[c] = *(const short8*)(Bn + (size_t)t * 8);
            }
            areg = *(const short8*)(Ap + (kt + 1) * 32);
        }
        const unsigned short* Bbuf = Bs[kt & 1];
#pragma unroll
        for (int s = 0; s < 8; s++) {
            int col = s * 16 + m;
            short8 b = *(const short8*)(&Bbuf[col * 32 + ((kq ^ ((col >> 1) & 3)) << 3)]);
            acc[s] = __builtin_amdgcn_mfma_f32_16x16x32_bf16(a, b, acc[s], 0, 0, 0);
        }
        if (kt < L1W / 32 - 1) {
            int nb = (kt + 1) & 1;
#pragma unroll
            for (int c = 0; c < 2; c++) {
                int t = tid + c * 256;
                int col = t >> 2, pp = t & 3;
                *(short8*)(&Bs[nb][col * 32 + ((pp ^ ((col >> 1) & 3)) << 3)]) = breg[c];
            }
        }
        __syncthreads();
    }
    int crow = row0 + kq * 4;
#pragma unroll
    for (int s = 0; s < 8; s++) {
        int col = s * 16 + m;
#pragma unroll
        for (int r = 0; r < 4; r++) {
            int row = crow + r;
            if (row < N) Ub[(size_t)row * L2WP + col] = f2bf(acc[s][r]);
        }
    }
}

// ---------------- fused width-256 fp8 prop over Y8 --------------------------
// Y8 phys layout: byte P = m*16 + t, logical col L = t*16 + m (t,m in [0,16)).
// Lane l: m = l>>2, t in {4(l&3)..4(l&3)+3}; reads one uint (4 fp8) per row.
// Gather = 256 B/row coalesced. 8-edge unroll, int2 edge records.
// t<8 (lanes jj<2): z1 -> relu(+b1) bf16 -> Hb[:,128:256] (scattered 2B).
// t>=8 (jj>=2): t2 -> fp8 T8 [n x 128 B], phys byte = m*8 + (t-8).

__global__ __launch_bounds__(256) void prop256f_k(const unsigned char* __restrict__ Y8,
                                                  unsigned short* __restrict__ Hb,
                                                  unsigned char* __restrict__ T8,
                                                  const int* __restrict__ rowptr,
                                                  const int2* __restrict__ csr,
                                                  const float* __restrict__ dinv,
                                                  const float* __restrict__ b1, int n) {
    int wave = threadIdx.x >> 6, lane = threadIdx.x & 63;
    int i = blockIdx.x * 4 + wave;
    if (i >= n) return;
    int beg = rowptr[i], end = rowptr[i + 1];
    float di = dinv[i];
    const unsigned int* sbase = (const unsigned int*)Y8 + lane;  // row stride 64 uints
    unsigned int sv = sbase[(size_t)i * 64];
    float w = di * di;
    f32x2 slo = __builtin_amdgcn_cvt_pk_f32_fp8(sv, false);
    f32x2 shi = __builtin_amdgcn_cvt_pk_f32_fp8(sv, true);
    float a0 = w * slo.x, a1 = w * slo.y, a2 = w * shi.x, a3 = w * shi.y;
    int k = beg;
    for (; k + 7 < end; k += 8) {
        int2 rr[8];
        unsigned int vv[8];
#pragma unroll
        for (int e = 0; e < 8; e++) rr[e] = csr[k + e];
#pragma unroll
        for (int e = 0; e < 8; e++) vv[e] = sbase[(size_t)rr[e].x * 64];
#pragma unroll
        for (int e = 0; e < 8; e++) {
            float we = __int_as_float(rr[e].y);
            f32x2 lo = __builtin_amdgcn_cvt_pk_f32_fp8(vv[e], false);
            f32x2 hi = __builtin_amdgcn_cvt_pk_f32_fp8(vv[e], true);
            a0 = fmaf(we, lo.x, a0);
            a1 = fmaf(we, lo.y, a1);
            a2 = fmaf(we, hi.x, a2);
            a3 = fmaf(we, hi.y, a3);
        }
    }
    for (; k < end; k++) {
        int2 r0 = csr[k];
        float w0 = __int_as_float(r0.y);
        unsigned int v0 = sbase[(size_t)r0.x * 64];
        f32x2 lo = __builtin_amdgcn_cvt_pk_f32_fp8(v0, false);
        f32x2 hi = __builtin_amdgcn_cvt_pk_f32_fp8(v0, true);
        a0 = fmaf(w0, lo.x, a0); a1 = fmaf(w0, lo.y, a1);
        a2 = fmaf(w0, hi.x, a2); a3 = fmaf(w0, hi.y, a3);
    }
    int m = lane >> 2, jj = lane & 3;
    if (jj < 2) {  // z1: logical cols L_j = (4*jj+j)*16 + m
        float av[4] = {a0, a1, a2, a3};
#pragma unroll
        for (int j = 0; j < 4; j++) {
            int L = (4 * jj + j) * 16 + m;
            Hb[(size_t)i * L1W + 128 + L] = f2bf(fmaxf(av[j] + b1[128 + L], 0.f));
        }
    } else {       // t2 -> T8 phys = m*8 + 4*(jj-2)
        unsigned int o = pack_fp8x4(a0, a1, a2, a3);
        *(unsigned int*)(T8 + (size_t)i * 128 + m * 8 + 4 * (jj - 2)) = o;
    }
}

// ---------------- width-128 fp8 prop: Hb[:,256:384] = relu(P(T8)+b1) --------
// T8 phys: byte = m*8 + u, logical z2 col L = u*16 + m (u in [0,8), m in [0,16)).
// Lane l: reads ushort (2 fp8) at byte 2l -> m = l>>2, u0 = (2l)&7.

__global__ __launch_bounds__(256) void prop128f_k(const unsigned char* __restrict__ T8,
                                                  unsigned short* __restrict__ Hb,
                                                  const int* __restrict__ rowptr,
                                                  const int2* __restrict__ csr,
                                                  const float* __restrict__ dinv,
                                                  const float* __restrict__ b1, int n) {
    int wave = threadIdx.x >> 6, lane = threadIdx.x & 63;
    int i = blockIdx.x * 4 + wave;
    if (i >= n) return;
    int beg = rowptr[i], end = rowptr[i + 1];
    float di = dinv[i];
    const unsigned short* sbase = (const unsigned short*)T8 + lane;  // row stride 64
    unsigned int sv = sbase[(size_t)i * 64];
    float w = di * di;
    f32x2 sd = __builtin_amdgcn_cvt_pk_f32_fp8(sv, false);
    float a0 = w * sd.x, a1 = w * sd.y;
    int k = beg;
    for (; k + 7 < end; k += 8) {
        int2 rr[8];
        unsigned int vv[8];
#pragma unroll
        for (int e = 0; e < 8; e++) rr[e] = csr[k + e];
#pragma unroll
        for (int e = 0; e < 8; e++) vv[e] = sbase[(size_t)rr[e].x * 64];
#pragma unroll
        for (int e = 0; e < 8; e++) {
            float we = __int_as_float(rr[e].y);
            f32x2 d = __builtin_amdgcn_cvt_pk_f32_fp8(vv[e], false);
            a0 = fmaf(we, d.x, a0);
            a1 = fmaf(we, d.y, a1);
        }
    }
    for (; k < end; k++) {
        int2 r0 = csr[k];
        float w0 = __int_as_float(r0.y);
        unsigned int v0 = sbase[(size_t)r0.x * 64];
        f32x2 d = __builtin_amdgcn_cvt_pk_f32_fp8(v0, false);
        a0 = fmaf(w0, d.x, a0); a1 = fmaf(w0, d.y, a1);
    }
    int m = lane >> 2, u0 = (2 * lane) & 7;
    int L0 = u0 * 16 + m, L1 = (u0 + 1) * 16 + m;
    Hb[(size_t)i * L1W + 256 + L0] = f2bf(fmaxf(a0 + b1[256 + L0], 0.f));
    Hb[(size_t)i * L1W + 256 + L1] = f2bf(fmaxf(a1 + b1[256 + L1], 0.f));
}

// ---------------- fused width-80 bf16 prop (layer 2), 4-edge unroll ---------

__global__ __launch_bounds__(256) void prop80b_k(const unsigned short* __restrict__ Ub,
                                                 unsigned short* __restrict__ T2a,
                                                 unsigned short* __restrict__ T2b,
                                                 const int* __restrict__ rowptr,
                                                 const int2* __restrict__ csr,
                                                 const float* __restrict__ dinv, int n) {
    int wave = threadIdx.x >> 6, lane = threadIdx.x & 63;
    int i = blockIdx.x * 4 + wave;
    if (i >= n) return;
    int beg = rowptr[i], end = rowptr[i + 1];
    float di = dinv[i];
    bool act = lane < 40;
    const unsigned int* sbase = (const unsigned int*)(Ub + 40) + lane;
    float a0 = 0.f, a1 = 0.f;
    if (act) {
        unsigned int sv = sbase[(size_t)i * 64];
        float w = di * di;
        a0 = w * bf2f((unsigned short)sv); a1 = w * bf2f((unsigned short)(sv >> 16));
    }
    int k = beg;
    for (; k + 3 < end; k += 4) {
        int2 r0 = csr[k], r1 = csr[k + 1], r2 = csr[k + 2], r3 = csr[k + 3];
        if (act) {
            unsigned int v0 = sbase[(size_t)r0.x * 64];
            unsigned int v1 = sbase[(size_t)r1.x * 64];
            unsigned int v2 = sbase[(size_t)r2.x * 64];
            unsigned int v3 = sbase[(size_t)r3.x * 64];
            float w0 = __int_as_float(r0.y), w1 = __int_as_float(r1.y);
            float w2 = __int_as_float(r2.y), w3 = __int_as_float(r3.y);
            a0 = fmaf(w0, bf2f((unsigned short)v0), a0); a1 = fmaf(w0, bf2f((unsigned short)(v0 >> 16)), a1);
            a0 = fmaf(w1, bf2f((unsigned short)v1), a0); a1 = fmaf(w1, bf2f((unsigned short)(v1 >> 16)), a1);
            a0 = fmaf(w2, bf2f((unsigned short)v2), a0); a1 = fmaf(w2, bf2f((unsigned short)(v2 >> 16)), a1);
            a0 = fmaf(w3, bf2f((unsigned short)v3), a0); a1 = fmaf(w3, bf2f((unsigned short)(v3 >> 16)), a1);
        }
    }
    for (; k < end; k++) {
        int2 r0 = csr[k];
        if (act) {
            float w0 = __int_as_float(r0.y);
            unsigned int v0 = sbase[(size_t)r0.x * 64];
            a0 = fmaf(w0, bf2f((unsigned short)v0), a0); a1 = fmaf(w0, bf2f((unsigned short)(v0 >> 16)), a1);
        }
    }
    if (act) {
        unsigned int o = (unsigned int)f2bf(a0) | ((unsigned int)f2bf(a1) << 16);
        if (lane < 20) *((unsigned int*)T2a + (size_t)i * 20 + lane) = o;
        else *((unsigned int*)T2b + (size_t)i * 20 + (lane - 20)) = o;
    }
}

// ---------------- fused second-hop prop + log_softmax -----------------------

__global__ __launch_bounds__(256) void lsm_prop_k(const unsigned short* __restrict__ Ub,
                                                  const unsigned short* __restrict__ T2a,
                                                  const unsigned short* __restrict__ T2b,
                                                  const int* __restrict__ rowptr,
                                                  const int2* __restrict__ csr,
                                                  const float* __restrict__ dinv,
                                                  const float* __restrict__ b2,
                                                  float* __restrict__ out, int n) {
    int wave = threadIdx.x >> 6;
    int lane = threadIdx.x & 63;
    int i = blockIdx.x * 4 + wave;
    if (i >= n) return;
    int beg = rowptr[i], end = rowptr[i + 1];
    float di = dinv[i];
    bool act = lane < 20;
    const unsigned int* sbase = (const unsigned int*)T2b + lane;
    float a0 = 0.f, a1 = 0.f;
    if (act) {
        unsigned int sv = sbase[(size_t)i * 20];
        float w = di * di;
        a0 = w * bf2f((unsigned short)sv); a1 = w * bf2f((unsigned short)(sv >> 16));
    }
    int k = beg;
    for (; k + 3 < end; k += 4) {
        int2 r0 = csr[k], r1 = csr[k + 1], r2 = csr[k + 2], r3 = csr[k + 3];
        if (act) {
            unsigned int v0 = sbase[(size_t)r0.x * 20];
            unsigned int v1 = sbase[(size_t)r1.x * 20];
            unsigned int v2 = sbase[(size_t)r2.x * 20];
            unsigned int v3 = sbase[(size_t)r3.x * 20];
            float w0 = __int_as_float(r0.y), w1 = __int_as_float(r1.y);
            float w2 = __int_as_float(r2.y), w3 = __int_as_float(r3.y);
            a0 = fmaf(w0, bf2f((unsigned short)v0), a0); a1 = fmaf(w0, bf2f((unsigned short)(v0 >> 16)), a1);
            a0 = fmaf(w1, bf2f((unsigned short)v1), a0); a1 = fmaf(w1, bf2f((unsigned short)(v1 >> 16)), a1);
            a0 = fmaf(w2, bf2f((unsigned short)v2), a0); a1 = fmaf(w2, bf2f((unsigned short)(v2 >> 16)), a1);
            a0 = fmaf(w3, bf2f((unsigned short)v3), a0); a1 = fmaf(w3, bf2f((unsigned short)(v3 >> 16)), a1);
        }
    }
    for (; k < end; k++) {
        int2 r0 = csr[k];
        if (act) {
            float w0 = __int_as_float(r0.y);
            unsigned int v0 = sbase[(size_t)r0.x * 20];
            a0 = fmaf(w0, bf2f((unsigned short)v0), a0); a1 = fmaf(w0, bf2f((unsigned short)(v0 >> 16)), a1);
        }
    }
    int j1 = lane + 64;
    int srcl = (j1 - 80) >> 1;
    float pa = __shfl(a0, srcl, 64);
    float pb = __shfl(a1, srcl, 64);
    float pv = ((j1 - 80) & 1) ? pb : pa;
    float v0, v1;
    {
        int j = lane;  // 0..63
        float v = (j >= 40) ? bf2f(T2a[(size_t)i * 40 + (j - 40)]) : bf2f(Ub[(size_t)i * L2WP + j]);
        v0 = v + b2[j];
    }
    if (j1 < 120) {
        float v = (j1 < 80) ? bf2f(T2a[(size_t)i * 40 + (j1 - 40)]) : pv;
        v1 = v + b2[j1];
    } else {
        v1 = -INFINITY;
    }
    float m = fmaxf(v0, v1);
    for (int off = 32; off; off >>= 1) m = fmaxf(m, __shfl_xor(m, off, 64));
    float s = expf(v0 - m) + ((j1 < 120) ? expf(v1 - m) : 0.f);
    for (int off = 32; off; off >>= 1) s += __shfl_xor(s, off, 64);
    float ls = logf(s) + m;
    out[(size_t)i * 120 + lane] = v0 - ls;
    if (j1 < 120) out[(size_t)i * 120 + j1] = v1 - ls;
}

// ---------------- launch ----------------

static inline size_t align256(size_t x) { return (x + 255) & ~(size_t)255; }

extern "C" void kernel_launch(void* const* d_in, const int* in_sizes, int n_in,
                              void* d_out, int out_size, void* d_ws, size_t ws_size,
                              hipStream_t stream) {
    const float* x = (const float*)d_in[0];
    const int* ei = (const int*)d_in[1];
    const float* W1_0 = (const float*)d_in[2];
    const float* W1_1 = (const float*)d_in[3];
    const float* W1_2 = (const float*)d_in[4];
    const float* b1 = (const float*)d_in[5];
    const float* W2_0 = (const float*)d_in[6];
    const float* W2_1 = (const float*)d_in[7];
    const float* W2_2 = (const float*)d_in[8];
    const float* b2 = (const float*)d_in[9];
    float* out = (float*)d_out;

    const int n = N_NODES;
    const int E = in_sizes[1] / 2;
    const int nb = (n + 255) / 256;

    char* p = (char*)d_ws;
    size_t off = 0;
    auto alloc = [&](size_t bytes) {
        void* r = p + off;
        off = align256(off + bytes);
        return r;
    };
    int* flag = (int*)alloc(4);
    int* cnt = (int*)alloc((size_t)n * 4);
    int* rowptr = (int*)alloc((size_t)(n + 1) * 4);
    int* fill = (int*)alloc((size_t)n * 4);
    int* bsum = (int*)alloc((size_t)nb * 4);
    float* dinv = (float*)alloc((size_t)n * 4);
    int2* csr = (int2*)alloc((size_t)E * 8);
    unsigned short* Bp1 = (unsigned short*)alloc((size_t)(F_IN / 32) * L1W * 32 * 2);
    unsigned short* Bp2 = (unsigned short*)alloc((size_t)(L1W / 32) * L2WP * 32 * 2);
    unsigned short* Hb = (unsigned short*)alloc((size_t)n * L1W * 2);
    unsigned char* Y8 = (unsigned char*)alloc((size_t)n * 256);
    unsigned char* T8 = (unsigned char*)alloc((size_t)n * 128);
    unsigned short* Ub = (unsigned short*)alloc((size_t)n * L2WP * 2);
    unsigned short* T2a = (unsigned short*)alloc((size_t)n * C_OUT * 2);
    unsigned short* T2b = (unsigned short*)alloc((size_t)n * C_OUT * 2);
    (void)ws_size;

    // 0. edge dtype detect
    detect_k<<<1, 256, 0, stream>>>(ei, flag);

    // 1. CSR build (conversion inlined into hist/scatter)
    hipMemsetAsync(cnt, 0, (size_t)n * 4, stream);
    hist_k<<<(E + 255) / 256, 256, 0, stream>>>(ei, flag, cnt, E);
    dinv_k<<<(n + 255) / 256, 256, 0, stream>>>(cnt, dinv, n);
    scan1_k<<<nb, 256, 0, stream>>>(cnt, bsum, n);
    scan2_k<<<1, 256, 0, stream>>>(bsum, rowptr + n, nb);
    scan3_k<<<nb, 256, 0, stream>>>(cnt, bsum, rowptr, fill, n);
    scatter_k<<<(E + 255) / 256, 256, 0, stream>>>(ei, flag, fill, csr, dinv, E);

    // 2. weight packing
    pack1b_k<<<((F_IN / 32) * L1W * 32 + 255) / 256, 256, 0, stream>>>(W1_0, W1_1, W1_2, Bp1);
    pack2b_k<<<((L1W / 32) * L2WP * 32 + 255) / 256, 256, 0, stream>>>(W2_0, W2_1, W2_2, Bp2);

    // 3. layer 1 GEMM (LDS-staged B; z1 -> Hb bf16, y2 -> Y8 fp8 transposed)
    mgemm1_k<<<(n + 63) / 64, 256, 0, stream>>>(x, Bp1, b1, Hb, Y8, n);
    // fused prop: Hb[:,128:256] = relu(P(y1)+b1); T8 = fp8(P(y2))
    prop256f_k<<<(n + 3) / 4, 256, 0, stream>>>(Y8, Hb, T8, rowptr, csr, dinv, b1, n);
    // Hb[:,256:384] = relu(P(T8)+b1)
    prop128f_k<<<(n + 3) / 4, 256, 0, stream>>>(T8, Hb, rowptr, csr, dinv, b1, n);

    // 4. layer 2 GEMM -> bf16 Ub (LDS-staged B)
    mgemm2_k<<<(n + 63) / 64, 256, 0, stream>>>(Hb, Bp2, Ub, n);
    // fused: T2a = P(u1), T2b = P(u2)
    prop80b_k<<<(n + 3) / 4, 256, 0, stream>>>(Ub, T2a, T2b, rowptr, csr, dinv, n);

    // 5. fused second hop + log_softmax
    lsm_prop_k<<<(n + 3) / 4, 256, 0, stream>>>(Ub, T2a, T2b, rowptr, csr, dinv, b2, out, n);
}